// Round 4
// baseline (4488.118 us; speedup 1.0000x reference)
//
#include <hip/hip_runtime.h>
#include <math.h>

#define TPB 256

typedef float v4f __attribute__((ext_vector_type(4)));

// ---------------------------------------------------------------------------
// ws layout (4-byte units):
//   cg     float[256]   @ 0
//   counts int[N]       @ 256
//   starts int[N+1]     @ 256+N
//   cursor int[N]       @ 257+2N
//   perm   int[E]
// ---------------------------------------------------------------------------

__device__ double dfact(int n){ double r = 1.0; for (int i = 2; i <= n; ++i) r *= (double)i; return r; }

__device__ void build_u(int l, double ur[5][5], double ui[5][5]){
  for (int i = 0; i < 5; ++i) for (int j = 0; j < 5; ++j){ ur[i][j] = 0.0; ui[i][j] = 0.0; }
  ur[l][l] = 1.0;
  double s = 1.0 / sqrt(2.0);
  for (int m = 1; m <= l; ++m){
    double sg = (m & 1) ? -1.0 : 1.0;
    ur[l + m][l + m] = sg * s;
    ur[l + m][l - m] = s;
    ui[l - m][l - m] = s;
    ui[l - m][l + m] = -sg * s;
  }
}

// One thread per CG output element (245 total). The re/im choice is the
// parity rule: T is purely real iff (l1+l2+l3) even, purely imaginary iff odd
// (equivalent to the reference's absmax test).
__global__ void cg_init_kernel(float* __restrict__ cg){
  int tid = threadIdx.x;
  if (tid >= 245) return;
  const int L1[9]  = {0,0,0,1,1,1,1,1,1};
  const int L2[9]  = {0,1,2,0,1,1,1,2,2};
  const int L3[9]  = {0,1,2,1,0,1,2,1,2};
  const int OFF[10] = {0,1,10,35,44,53,80,125,170,245};
  int p = 0;
  while (p < 8 && tid >= OFF[p+1]) ++p;
  int idx = tid - OFF[p];
  int l1 = L1[p], l2 = L2[p], l3 = L3[p];
  int n1 = 2*l1+1, n2 = 2*l2+1, n3 = 2*l3+1;
  int c = idx % n3; int ab = idx / n3; int b = ab % n2; int a = ab / n2;

  // complex-basis CG for this path
  double Cc[5][5][5];
  for (int i = 0; i < 5; ++i) for (int j = 0; j < 5; ++j) for (int k = 0; k < 5; ++k) Cc[i][j][k] = 0.0;
  for (int m1 = -l1; m1 <= l1; ++m1) for (int m2 = -l2; m2 <= l2; ++m2){
    int m3 = m1 + m2;
    if (m3 < -l3 || m3 > l3) continue;
    double pref = sqrt((double)(2*l3+1) * dfact(l1+l2-l3) * dfact(l1-l2+l3) * dfact(-l1+l2+l3) / dfact(l1+l2+l3+1));
    pref *= sqrt(dfact(l3+m3)*dfact(l3-m3)*dfact(l1-m1)*dfact(l1+m1)*dfact(l2-m2)*dfact(l2+m2));
    double s = 0.0;
    for (int k = 0; k <= l1 + l2 - l3; ++k){
      int a0 = k, a1 = l1+l2-l3-k, a2 = l1-m1-k, a3 = l2+m2-k, a4 = l3-l2+m1+k, a5 = l3-l1-m2+k;
      if (a0 < 0 || a1 < 0 || a2 < 0 || a3 < 0 || a4 < 0 || a5 < 0) continue;
      double d = dfact(a0)*dfact(a1)*dfact(a2)*dfact(a3)*dfact(a4)*dfact(a5);
      s += ((k & 1) ? -1.0 : 1.0) / d;
    }
    Cc[m1+l1][m2+l2][m3+l3] = pref * s;
  }

  double U1r[5][5], U1i[5][5], U2r[5][5], U2i[5][5], U3r[5][5], U3i[5][5];
  build_u(l1, U1r, U1i); build_u(l2, U2r, U2i); build_u(l3, U3r, U3i);

  double sr = 0.0, si = 0.0;
  for (int m = 0; m < n1; ++m) for (int n = 0; n < n2; ++n) for (int o = 0; o < n3; ++o){
    double cc = Cc[m][n][o];
    if (cc == 0.0) continue;
    double xre = U1r[a][m], xim = U1i[a][m];
    double yre = U2r[b][n], yim = U2i[b][n];
    double zr = xre*yre - xim*yim, zi = xre*yim + xim*yre;
    double wr = U3r[c][o], wi = -U3i[c][o];
    double pr = zr*wr - zi*wi, pi = zr*wi + zi*wr;
    sr += pr * cc; si += pi * cc;
  }
  int use_re = (((l1 + l2 + l3) & 1) == 0);
  cg[tid] = (float)(use_re ? sr : si);
}

// ---------------- CSR build ----------------

__global__ void hist_kernel(const int* __restrict__ ei, int* __restrict__ counts, int E){
  int e = blockIdx.x * TPB + threadIdx.x;
  if (e < E) atomicAdd(&counts[ei[2*e + 1]], 1);
}

__global__ void scan_kernel(const int* __restrict__ counts, int* __restrict__ starts,
                            int* __restrict__ cursor, int N){
  __shared__ int part[1024];
  int t = threadIdx.x;
  int T = (N + 1023) >> 10;
  int base = t * T;
  int s = 0;
  for (int i = 0; i < T; ++i){ int idx = base + i; if (idx < N) s += counts[idx]; }
  part[t] = s; __syncthreads();
  for (int off = 1; off < 1024; off <<= 1){
    int v = (t >= off) ? part[t - off] : 0;
    __syncthreads();
    part[t] += v;
    __syncthreads();
  }
  int excl = (t == 0) ? 0 : part[t - 1];
  for (int i = 0; i < T; ++i){
    int idx = base + i;
    if (idx < N){ starts[idx] = excl; cursor[idx] = excl; excl += counts[idx]; }
  }
  if (t == 1023) starts[N] = part[1023];
}

__global__ void perm_kernel(const int* __restrict__ ei, int* __restrict__ cursor,
                            int* __restrict__ perm, int E){
  int e = blockIdx.x * TPB + threadIdx.x;
  if (e < E){
    int pos = atomicAdd(&cursor[ei[2*e + 1]], 1);
    perm[pos] = e;
  }
}

// ---------------- per-edge compute ----------------

__device__ __forceinline__ float silu_f(float x){
  float t = __expf(-x);
  return x * __builtin_amdgcn_rcpf(1.0f + t);
}

#define SEGSUM(v) { float _o; \
  _o = __shfl_up(v, 1);  v += samef[0]*_o; \
  _o = __shfl_up(v, 2);  v += samef[1]*_o; \
  _o = __shfl_up(v, 4);  v += samef[2]*_o; \
  _o = __shfl_up(v, 8);  v += samef[3]*_o; \
  _o = __shfl_up(v, 16); v += samef[4]*_o; \
  _o = __shfl_up(v, 32); v += samef[5]*_o; }

__global__ void __launch_bounds__(TPB, 2) tfn_sorted_kernel(
    const float* __restrict__ nf, const float* __restrict__ ef,
    const float* __restrict__ ev, const int* __restrict__ ei,
    const float* __restrict__ W0, const float* __restrict__ W1,
    const float* __restrict__ W2, const float* __restrict__ cg,
    const int* __restrict__ perm, float* __restrict__ out, int E)
{
  int t = blockIdx.x * TPB + threadIdx.x;
  bool valid = (t < E);
  int e = perm[valid ? t : (E - 1)];
  int d = valid ? ei[2*e + 1] : -1;
  int lane = threadIdx.x & 63;

  float samef[6];
  #pragma unroll
  for (int s = 0; s < 6; ++s){
    int off = 1 << s;
    int od = __shfl_up(d, off);
    samef[s] = (lane >= off && od == d) ? 1.0f : 0.0f;
  }
  int nd = __shfl_down(d, 1);
  bool tail = valid && ((lane == 63) || (nd != d));

  // ---- edge features (4x dwordx4) ----
  float f0[16];
  {
    const v4f* efv = (const v4f*)(ef + (size_t)e * 16);
    *(v4f*)&f0[0]  = efv[0];
    *(v4f*)&f0[4]  = efv[1];
    *(v4f*)&f0[8]  = efv[2];
    *(v4f*)&f0[12] = efv[3];
  }

  // ---- MLP layer 0: a = f0 @ W0 (W0 rows contiguous, x4 loads) ----
  float acc[64];
  #pragma unroll
  for (int j = 0; j < 64; ++j) acc[j] = 0.f;
  #pragma unroll
  for (int q = 0; q < 16; ++q){
    float fq = f0[q];
    const v4f* w0r = (const v4f*)(W0 + q * 64);
    #pragma unroll
    for (int k4 = 0; k4 < 16; ++k4){
      v4f w = w0r[k4];
      acc[4*k4+0] += fq * w.x; acc[4*k4+1] += fq * w.y;
      acc[4*k4+2] += fq * w.z; acc[4*k4+3] += fq * w.w;
    }
  }

  // ---- MLP layer 1: h1 = silu(acc) @ W1 (x4 loads) ----
  float h1[64];
  #pragma unroll
  for (int j = 0; j < 64; ++j) h1[j] = 0.f;
  for (int k = 0; k < 64; ++k){
    float g = silu_f(acc[k]);
    const v4f* w1r = (const v4f*)(W1 + k * 64);
    #pragma unroll
    for (int j4 = 0; j4 < 16; ++j4){
      v4f w = w1r[j4];
      h1[4*j4+0] += g * w.x; h1[4*j4+1] += g * w.y;
      h1[4*j4+2] += g * w.z; h1[4*j4+3] += g * w.w;
    }
  }
  #pragma unroll
  for (int j = 0; j < 64; ++j) h1[j] = silu_f(h1[j]);

  // ---- spherical harmonics ----
  float ex = ev[(size_t)e*3+0], eyv = ev[(size_t)e*3+1], ezv = ev[(size_t)e*3+2];
  float ri = __builtin_amdgcn_rcpf(sqrtf(ex*ex + eyv*eyv + ezv*ezv) + 1e-12f);
  float X = ex*ri, Y = eyv*ri, Z = ezv*ri;
  const float s3 = 1.7320508075688772f;
  float Y1v[3] = {Y, Z, X};
  float Y2v[5] = {s3*X*Y, s3*Y*Z, 0.5f*(3.f*Z*Z - 1.f), s3*X*Z, 0.5f*s3*(X*X - Y*Y)};

  // ---- Y-contracted CG ----
  float B0 = cg[0];
  float B1[3], B2[5], B3[9], B4[3], B5[9], B6[15], B7[9], B8[15];
  #pragma unroll
  for (int c = 0; c < 3; ++c){ float s = 0.f;
    #pragma unroll
    for (int b = 0; b < 3; ++b) s += cg[1 + b*3 + c] * Y1v[b];
    B1[c] = s; }
  #pragma unroll
  for (int c = 0; c < 5; ++c){ float s = 0.f;
    #pragma unroll
    for (int b = 0; b < 5; ++b) s += cg[10 + b*5 + c] * Y2v[b];
    B2[c] = s; }
  #pragma unroll
  for (int i = 0; i < 9; ++i) B3[i] = cg[35 + i];
  #pragma unroll
  for (int a = 0; a < 3; ++a){ float s = 0.f;
    #pragma unroll
    for (int b = 0; b < 3; ++b) s += cg[44 + a*3 + b] * Y1v[b];
    B4[a] = s; }
  #pragma unroll
  for (int a = 0; a < 3; ++a)
    #pragma unroll
    for (int c = 0; c < 3; ++c){ float s = 0.f;
      #pragma unroll
      for (int b = 0; b < 3; ++b) s += cg[53 + (a*3 + b)*3 + c] * Y1v[b];
      B5[a*3 + c] = s; }
  #pragma unroll
  for (int a = 0; a < 3; ++a)
    #pragma unroll
    for (int c = 0; c < 5; ++c){ float s = 0.f;
      #pragma unroll
      for (int b = 0; b < 3; ++b) s += cg[80 + (a*3 + b)*5 + c] * Y1v[b];
      B6[a*5 + c] = s; }
  #pragma unroll
  for (int a = 0; a < 3; ++a)
    #pragma unroll
    for (int c = 0; c < 3; ++c){ float s = 0.f;
      #pragma unroll
      for (int b = 0; b < 5; ++b) s += cg[125 + (a*5 + b)*3 + c] * Y2v[b];
      B7[a*3 + c] = s; }
  #pragma unroll
  for (int a = 0; a < 3; ++a)
    #pragma unroll
    for (int c = 0; c < 5; ++c){ float s = 0.f;
      #pragma unroll
      for (int b = 0; b < 5; ++b) s += cg[170 + (a*5 + b)*5 + c] * Y2v[b];
      B8[a*5 + c] = s; }

  int src = ei[2*e];
  const float* xr = nf + (size_t)src * 128;
  float* orow = out + (size_t)(d < 0 ? 0 : d) * 288;

  // ---- channel loop, tiled by 4 (x4 W2 loads) ----
  for (int u4 = 0; u4 < 8; ++u4){
    v4f wv[9];
    #pragma unroll
    for (int p = 0; p < 9; ++p) wv[p] = (v4f)(0.f);
    for (int k = 0; k < 64; ++k){
      float hk = h1[k];
      const v4f* w2r = (const v4f*)(W2 + k * 288 + 4 * u4);
      #pragma unroll
      for (int p = 0; p < 9; ++p){
        v4f w = w2r[p * 8];          // p*32 floats
        wv[p] += hk * w;
      }
    }

    v4f x0v = *(const v4f*)(xr + 4 * u4);
    float xl[12];
    {
      const v4f* xp = (const v4f*)(xr + 32 + 12 * u4);
      *(v4f*)&xl[0] = xp[0];
      *(v4f*)&xl[4] = xp[1];
      *(v4f*)&xl[8] = xp[2];
    }

    #pragma unroll
    for (int j = 0; j < 4; ++j){
      int u = 4 * u4 + j;
      float wvj[9];
      #pragma unroll
      for (int p = 0; p < 9; ++p) wvj[p] = silu_f(wv[p][j]);

      float x0 = x0v[j];
      float xa = xl[3*j + 0], xb = xl[3*j + 1], xc = xl[3*j + 2];

      float a0 = wvj[0] * (B0 * x0)
               + wvj[4] * (B4[0]*xa + B4[1]*xb + B4[2]*xc);
      float a1[3];
      #pragma unroll
      for (int c = 0; c < 3; ++c)
        a1[c] = wvj[1] * (B1[c] * x0)
              + wvj[3] * (B3[c]*xa + B3[3+c]*xb + B3[6+c]*xc)
              + wvj[5] * (B5[c]*xa + B5[3+c]*xb + B5[6+c]*xc)
              + wvj[7] * (B7[c]*xa + B7[3+c]*xb + B7[6+c]*xc);
      float a2[5];
      #pragma unroll
      for (int c = 0; c < 5; ++c)
        a2[c] = wvj[2] * (B2[c] * x0)
              + wvj[6] * (B6[c]*xa + B6[5+c]*xb + B6[10+c]*xc)
              + wvj[8] * (B8[c]*xa + B8[5+c]*xb + B8[10+c]*xc);

      SEGSUM(a0);
      #pragma unroll
      for (int c = 0; c < 3; ++c) SEGSUM(a1[c]);
      #pragma unroll
      for (int c = 0; c < 5; ++c) SEGSUM(a2[c]);

      if (tail){
        unsafeAtomicAdd(&orow[u], a0);
        #pragma unroll
        for (int c = 0; c < 3; ++c) unsafeAtomicAdd(&orow[32 + 3*u + c], a1[c]);
        #pragma unroll
        for (int c = 0; c < 5; ++c) unsafeAtomicAdd(&orow[128 + 5*u + c], a2[c]);
      }
    }
  }
}

// fallback (atomic per edge) if ws too small for CSR arrays
__global__ void __launch_bounds__(TPB, 2) tfn_atomic_kernel(
    const float* __restrict__ nf, const float* __restrict__ ef,
    const float* __restrict__ ev, const int* __restrict__ ei,
    const float* __restrict__ W0, const float* __restrict__ W1,
    const float* __restrict__ W2, const float* __restrict__ cg,
    float* __restrict__ out, int E)
{
  int e = blockIdx.x * TPB + threadIdx.x;
  if (e >= E) return;

  float f0[16];
  #pragma unroll
  for (int q = 0; q < 16; ++q) f0[q] = ef[(size_t)e*16 + q];
  float h1[64];
  #pragma unroll
  for (int j = 0; j < 64; ++j) h1[j] = 0.f;
  for (int k = 0; k < 64; ++k){
    float a = 0.f;
    #pragma unroll
    for (int q = 0; q < 16; ++q) a += f0[q] * W0[q*64 + k];
    float g = silu_f(a);
    #pragma unroll
    for (int j = 0; j < 64; ++j) h1[j] += g * W1[k*64 + j];
  }
  #pragma unroll
  for (int j = 0; j < 64; ++j) h1[j] = silu_f(h1[j]);

  float ex = ev[(size_t)e*3+0], eyv = ev[(size_t)e*3+1], ezv = ev[(size_t)e*3+2];
  float ri = __builtin_amdgcn_rcpf(sqrtf(ex*ex + eyv*eyv + ezv*ezv) + 1e-12f);
  float X = ex*ri, Y = eyv*ri, Z = ezv*ri;
  const float s3 = 1.7320508075688772f;
  float Y1v[3] = {Y, Z, X};
  float Y2v[5] = {s3*X*Y, s3*Y*Z, 0.5f*(3.f*Z*Z - 1.f), s3*X*Z, 0.5f*s3*(X*X - Y*Y)};

  float B0 = cg[0];
  float B1[3], B2[5], B3[9], B4[3], B5[9], B6[15], B7[9], B8[15];
  #pragma unroll
  for (int c = 0; c < 3; ++c){ float s = 0.f;
    #pragma unroll
    for (int b = 0; b < 3; ++b) s += cg[1 + b*3 + c] * Y1v[b];
    B1[c] = s; }
  #pragma unroll
  for (int c = 0; c < 5; ++c){ float s = 0.f;
    #pragma unroll
    for (int b = 0; b < 5; ++b) s += cg[10 + b*5 + c] * Y2v[b];
    B2[c] = s; }
  #pragma unroll
  for (int i = 0; i < 9; ++i) B3[i] = cg[35 + i];
  #pragma unroll
  for (int a = 0; a < 3; ++a){ float s = 0.f;
    #pragma unroll
    for (int b = 0; b < 3; ++b) s += cg[44 + a*3 + b] * Y1v[b];
    B4[a] = s; }
  #pragma unroll
  for (int a = 0; a < 3; ++a)
    #pragma unroll
    for (int c = 0; c < 3; ++c){ float s = 0.f;
      #pragma unroll
      for (int b = 0; b < 3; ++b) s += cg[53 + (a*3 + b)*3 + c] * Y1v[b];
      B5[a*3 + c] = s; }
  #pragma unroll
  for (int a = 0; a < 3; ++a)
    #pragma unroll
    for (int c = 0; c < 5; ++c){ float s = 0.f;
      #pragma unroll
      for (int b = 0; b < 3; ++b) s += cg[80 + (a*3 + b)*5 + c] * Y1v[b];
      B6[a*5 + c] = s; }
  #pragma unroll
  for (int a = 0; a < 3; ++a)
    #pragma unroll
    for (int c = 0; c < 3; ++c){ float s = 0.f;
      #pragma unroll
      for (int b = 0; b < 5; ++b) s += cg[125 + (a*5 + b)*3 + c] * Y2v[b];
      B7[a*3 + c] = s; }
  #pragma unroll
  for (int a = 0; a < 3; ++a)
    #pragma unroll
    for (int c = 0; c < 5; ++c){ float s = 0.f;
      #pragma unroll
      for (int b = 0; b < 5; ++b) s += cg[170 + (a*5 + b)*5 + c] * Y2v[b];
      B8[a*5 + c] = s; }

  int src = ei[2*e], dst = ei[2*e + 1];
  const float* xr = nf + (size_t)src * 128;
  float* orow = out + (size_t)dst * 288;

  for (int u = 0; u < 32; ++u){
    float wv[9];
    #pragma unroll
    for (int p = 0; p < 9; ++p) wv[p] = 0.f;
    #pragma unroll
    for (int k = 0; k < 64; ++k){
      float hk = h1[k];
      #pragma unroll
      for (int p = 0; p < 9; ++p) wv[p] += hk * W2[k*288 + p*32 + u];
    }
    #pragma unroll
    for (int p = 0; p < 9; ++p) wv[p] = silu_f(wv[p]);

    float x0 = xr[u];
    float xa = xr[32 + 3*u + 0], xb = xr[32 + 3*u + 1], xc = xr[32 + 3*u + 2];

    float a0 = wv[0] * (B0 * x0)
             + wv[4] * (B4[0]*xa + B4[1]*xb + B4[2]*xc);
    float a1[3];
    #pragma unroll
    for (int c = 0; c < 3; ++c)
      a1[c] = wv[1] * (B1[c] * x0)
            + wv[3] * (B3[c]*xa + B3[3+c]*xb + B3[6+c]*xc)
            + wv[5] * (B5[c]*xa + B5[3+c]*xb + B5[6+c]*xc)
            + wv[7] * (B7[c]*xa + B7[3+c]*xb + B7[6+c]*xc);
    float a2[5];
    #pragma unroll
    for (int c = 0; c < 5; ++c)
      a2[c] = wv[2] * (B2[c] * x0)
            + wv[6] * (B6[c]*xa + B6[5+c]*xb + B6[10+c]*xc)
            + wv[8] * (B8[c]*xa + B8[5+c]*xb + B8[10+c]*xc);

    unsafeAtomicAdd(&orow[u], a0);
    #pragma unroll
    for (int c = 0; c < 3; ++c) unsafeAtomicAdd(&orow[32 + 3*u + c], a1[c]);
    #pragma unroll
    for (int c = 0; c < 5; ++c) unsafeAtomicAdd(&orow[128 + 5*u + c], a2[c]);
  }
}

extern "C" void kernel_launch(void* const* d_in, const int* in_sizes, int n_in,
                              void* d_out, int out_size, void* d_ws, size_t ws_size,
                              hipStream_t stream)
{
  const float* nf = (const float*)d_in[0];
  const float* ef = (const float*)d_in[1];
  const float* ev = (const float*)d_in[2];
  const int*   ei = (const int*)  d_in[3];
  const float* W0 = (const float*)d_in[4];
  const float* W1 = (const float*)d_in[5];
  const float* W2 = (const float*)d_in[6];
  float* out = (float*)d_out;

  int E = in_sizes[3] / 2;
  int N = in_sizes[0] / 128;

  float* cg     = (float*)d_ws;                       // 256
  int*   counts = (int*)d_ws + 256;                   // N
  int*   starts = counts + N;                         // N+1
  int*   cursor = starts + N + 1;                     // N
  int*   perm   = cursor + N;                         // E
  size_t need_bytes = (size_t)(256 + 3*N + 1 + E) * 4;

  cg_init_kernel<<<1, 256, 0, stream>>>(cg);
  hipMemsetAsync(d_out, 0, (size_t)out_size * sizeof(float), stream);

  if (ws_size >= need_bytes){
    hipMemsetAsync(counts, 0, (size_t)N * sizeof(int), stream);
    hist_kernel<<<(E + TPB - 1) / TPB, TPB, 0, stream>>>(ei, counts, E);
    scan_kernel<<<1, 1024, 0, stream>>>(counts, starts, cursor, N);
    perm_kernel<<<(E + TPB - 1) / TPB, TPB, 0, stream>>>(ei, cursor, perm, E);
    tfn_sorted_kernel<<<(E + TPB - 1) / TPB, TPB, 0, stream>>>(nf, ef, ev, ei, W0, W1, W2, cg, perm, out, E);
  } else {
    tfn_atomic_kernel<<<(E + TPB - 1) / TPB, TPB, 0, stream>>>(nf, ef, ev, ei, W0, W1, W2, cg, out, E);
  }
}

// Round 5
// 2075.900 us; speedup vs baseline: 2.1620x; 2.1620x over previous
//
#include <hip/hip_runtime.h>
#include <math.h>

#define TPB 256

typedef float v4f __attribute__((ext_vector_type(4)));

// ---------------------------------------------------------------------------
// ws layout (4-byte units):
//   cg     float[256]   @ 0
//   counts int[N]       @ 256
//   starts int[N+1]     @ 256+N
//   cursor int[N]       @ 257+2N
//   perm   int[E]
// ---------------------------------------------------------------------------

__device__ double dfact(int n){ double r = 1.0; for (int i = 2; i <= n; ++i) r *= (double)i; return r; }

__device__ void build_u(int l, double ur[5][5], double ui[5][5]){
  for (int i = 0; i < 5; ++i) for (int j = 0; j < 5; ++j){ ur[i][j] = 0.0; ui[i][j] = 0.0; }
  ur[l][l] = 1.0;
  double s = 1.0 / sqrt(2.0);
  for (int m = 1; m <= l; ++m){
    double sg = (m & 1) ? -1.0 : 1.0;
    ur[l + m][l + m] = sg * s;
    ur[l + m][l - m] = s;
    ui[l - m][l - m] = s;
    ui[l - m][l + m] = -sg * s;
  }
}

// One thread per CG output element (245 total). Re/im choice = parity rule.
__global__ void cg_init_kernel(float* __restrict__ cg){
  int tid = threadIdx.x;
  if (tid >= 245) return;
  const int L1[9]  = {0,0,0,1,1,1,1,1,1};
  const int L2[9]  = {0,1,2,0,1,1,1,2,2};
  const int L3[9]  = {0,1,2,1,0,1,2,1,2};
  const int OFF[10] = {0,1,10,35,44,53,80,125,170,245};
  int p = 0;
  while (p < 8 && tid >= OFF[p+1]) ++p;
  int idx = tid - OFF[p];
  int l1 = L1[p], l2 = L2[p], l3 = L3[p];
  int n1 = 2*l1+1, n2 = 2*l2+1, n3 = 2*l3+1;
  int c = idx % n3; int ab = idx / n3; int b = ab % n2; int a = ab / n2;

  double Cc[5][5][5];
  for (int i = 0; i < 5; ++i) for (int j = 0; j < 5; ++j) for (int k = 0; k < 5; ++k) Cc[i][j][k] = 0.0;
  for (int m1 = -l1; m1 <= l1; ++m1) for (int m2 = -l2; m2 <= l2; ++m2){
    int m3 = m1 + m2;
    if (m3 < -l3 || m3 > l3) continue;
    double pref = sqrt((double)(2*l3+1) * dfact(l1+l2-l3) * dfact(l1-l2+l3) * dfact(-l1+l2+l3) / dfact(l1+l2+l3+1));
    pref *= sqrt(dfact(l3+m3)*dfact(l3-m3)*dfact(l1-m1)*dfact(l1+m1)*dfact(l2-m2)*dfact(l2+m2));
    double s = 0.0;
    for (int k = 0; k <= l1 + l2 - l3; ++k){
      int a0 = k, a1 = l1+l2-l3-k, a2 = l1-m1-k, a3 = l2+m2-k, a4 = l3-l2+m1+k, a5 = l3-l1-m2+k;
      if (a0 < 0 || a1 < 0 || a2 < 0 || a3 < 0 || a4 < 0 || a5 < 0) continue;
      double d = dfact(a0)*dfact(a1)*dfact(a2)*dfact(a3)*dfact(a4)*dfact(a5);
      s += ((k & 1) ? -1.0 : 1.0) / d;
    }
    Cc[m1+l1][m2+l2][m3+l3] = pref * s;
  }

  double U1r[5][5], U1i[5][5], U2r[5][5], U2i[5][5], U3r[5][5], U3i[5][5];
  build_u(l1, U1r, U1i); build_u(l2, U2r, U2i); build_u(l3, U3r, U3i);

  double sr = 0.0, si = 0.0;
  for (int m = 0; m < n1; ++m) for (int n = 0; n < n2; ++n) for (int o = 0; o < n3; ++o){
    double cc = Cc[m][n][o];
    if (cc == 0.0) continue;
    double xre = U1r[a][m], xim = U1i[a][m];
    double yre = U2r[b][n], yim = U2i[b][n];
    double zr = xre*yre - xim*yim, zi = xre*yim + xim*yre;
    double wr = U3r[c][o], wi = -U3i[c][o];
    double pr = zr*wr - zi*wi, pi = zr*wi + zi*wr;
    sr += pr * cc; si += pi * cc;
  }
  int use_re = (((l1 + l2 + l3) & 1) == 0);
  cg[tid] = (float)(use_re ? sr : si);
}

// ---------------- CSR build ----------------

__global__ void hist_kernel(const int* __restrict__ ei, int* __restrict__ counts, int E){
  int e = blockIdx.x * TPB + threadIdx.x;
  if (e < E) atomicAdd(&counts[ei[2*e + 1]], 1);
}

__global__ void scan_kernel(const int* __restrict__ counts, int* __restrict__ starts,
                            int* __restrict__ cursor, int N){
  __shared__ int part[1024];
  int t = threadIdx.x;
  int T = (N + 1023) >> 10;
  int base = t * T;
  int s = 0;
  for (int i = 0; i < T; ++i){ int idx = base + i; if (idx < N) s += counts[idx]; }
  part[t] = s; __syncthreads();
  for (int off = 1; off < 1024; off <<= 1){
    int v = (t >= off) ? part[t - off] : 0;
    __syncthreads();
    part[t] += v;
    __syncthreads();
  }
  int excl = (t == 0) ? 0 : part[t - 1];
  for (int i = 0; i < T; ++i){
    int idx = base + i;
    if (idx < N){ starts[idx] = excl; cursor[idx] = excl; excl += counts[idx]; }
  }
  if (t == 1023) starts[N] = part[1023];
}

__global__ void perm_kernel(const int* __restrict__ ei, int* __restrict__ cursor,
                            int* __restrict__ perm, int E){
  int e = blockIdx.x * TPB + threadIdx.x;
  if (e < E){
    int pos = atomicAdd(&cursor[ei[2*e + 1]], 1);
    perm[pos] = e;
  }
}

// ---------------- per-edge compute ----------------

__device__ __forceinline__ float silu_f(float x){
  float t = __expf(-x);
  return x * __builtin_amdgcn_rcpf(1.0f + t);
}

#define SEGSUM(v) { float _o; \
  _o = __shfl_up(v, 1);  v += samef[0]*_o; \
  _o = __shfl_up(v, 2);  v += samef[1]*_o; \
  _o = __shfl_up(v, 4);  v += samef[2]*_o; \
  _o = __shfl_up(v, 8);  v += samef[3]*_o; \
  _o = __shfl_up(v, 16); v += samef[4]*_o; \
  _o = __shfl_up(v, 32); v += samef[5]*_o; }

__global__ void __launch_bounds__(TPB, 2) tfn_sorted_kernel(
    const float* __restrict__ nf, const float* __restrict__ ef,
    const float* __restrict__ ev, const int* __restrict__ ei,
    const float* __restrict__ W0, const float* __restrict__ W1,
    const float* __restrict__ W2, const float* __restrict__ cg,
    const int* __restrict__ perm, float* __restrict__ out, int E)
{
  // h1 staged per-thread in LDS: [k][tid]. Same-thread write/read -> no barrier.
  // Bank: (k*256+tid)%32 = tid%32 -> 2 lanes/bank (free).
  __shared__ float h1s[64 * TPB];   // 64 KB

  const int tid = threadIdx.x;
  int t = blockIdx.x * TPB + tid;
  bool valid = (t < E);
  int e = perm[valid ? t : (E - 1)];
  int d = valid ? ei[2*e + 1] : -1;
  int lane = tid & 63;

  float samef[6];
  #pragma unroll
  for (int s = 0; s < 6; ++s){
    int off = 1 << s;
    int od = __shfl_up(d, off);
    samef[s] = (lane >= off && od == d) ? 1.0f : 0.0f;
  }
  int nd = __shfl_down(d, 1);
  bool tail = valid && ((lane == 63) || (nd != d));

  // ---- edge features (4x dwordx4) ----
  float f0[16];
  {
    const v4f* efv = (const v4f*)(ef + (size_t)e * 16);
    *(v4f*)&f0[0]  = efv[0];
    *(v4f*)&f0[4]  = efv[1];
    *(v4f*)&f0[8]  = efv[2];
    *(v4f*)&f0[12] = efv[3];
  }

  // ---- MLP layer 0 ----
  float acc[64];
  #pragma unroll
  for (int j = 0; j < 64; ++j) acc[j] = 0.f;
  #pragma unroll
  for (int q = 0; q < 16; ++q){
    float fq = f0[q];
    const v4f* w0r = (const v4f*)(W0 + q * 64);
    #pragma unroll
    for (int k4 = 0; k4 < 16; ++k4){
      v4f w = w0r[k4];
      acc[4*k4+0] += fq * w.x; acc[4*k4+1] += fq * w.y;
      acc[4*k4+2] += fq * w.z; acc[4*k4+3] += fq * w.w;
    }
  }
  #pragma unroll
  for (int j = 0; j < 64; ++j) acc[j] = silu_f(acc[j]);   // acc = g

  // ---- MLP layer 1, j-tiles of 16, results to LDS ----
  #pragma unroll 1
  for (int jt = 0; jt < 4; ++jt){
    float a1[16];
    #pragma unroll
    for (int j = 0; j < 16; ++j) a1[j] = 0.f;
    for (int k = 0; k < 64; ++k){
      float g = acc[k];
      const v4f* w1r = (const v4f*)(W1 + k * 64 + jt * 16);
      #pragma unroll
      for (int j4 = 0; j4 < 4; ++j4){
        v4f w = w1r[j4];
        a1[4*j4+0] += g * w.x; a1[4*j4+1] += g * w.y;
        a1[4*j4+2] += g * w.z; a1[4*j4+3] += g * w.w;
      }
    }
    #pragma unroll
    for (int j = 0; j < 16; ++j)
      h1s[(jt*16 + j) * TPB + tid] = silu_f(a1[j]);
  }

  // ---- spherical harmonics ----
  float ex = ev[(size_t)e*3+0], eyv = ev[(size_t)e*3+1], ezv = ev[(size_t)e*3+2];
  float ri = __builtin_amdgcn_rcpf(sqrtf(ex*ex + eyv*eyv + ezv*ezv) + 1e-12f);
  float X = ex*ri, Y = eyv*ri, Z = ezv*ri;
  const float s3 = 1.7320508075688772f;
  float Y1v[3] = {Y, Z, X};
  float Y2v[5] = {s3*X*Y, s3*Y*Z, 0.5f*(3.f*Z*Z - 1.f), s3*X*Z, 0.5f*s3*(X*X - Y*Y)};

  // ---- Y-contracted CG ----
  float B0 = cg[0];
  float B1[3], B2[5], B3[9], B4[3], B5[9], B6[15], B7[9], B8[15];
  #pragma unroll
  for (int c = 0; c < 3; ++c){ float s = 0.f;
    #pragma unroll
    for (int b = 0; b < 3; ++b) s += cg[1 + b*3 + c] * Y1v[b];
    B1[c] = s; }
  #pragma unroll
  for (int c = 0; c < 5; ++c){ float s = 0.f;
    #pragma unroll
    for (int b = 0; b < 5; ++b) s += cg[10 + b*5 + c] * Y2v[b];
    B2[c] = s; }
  #pragma unroll
  for (int i = 0; i < 9; ++i) B3[i] = cg[35 + i];
  #pragma unroll
  for (int a = 0; a < 3; ++a){ float s = 0.f;
    #pragma unroll
    for (int b = 0; b < 3; ++b) s += cg[44 + a*3 + b] * Y1v[b];
    B4[a] = s; }
  #pragma unroll
  for (int a = 0; a < 3; ++a)
    #pragma unroll
    for (int c = 0; c < 3; ++c){ float s = 0.f;
      #pragma unroll
      for (int b = 0; b < 3; ++b) s += cg[53 + (a*3 + b)*3 + c] * Y1v[b];
      B5[a*3 + c] = s; }
  #pragma unroll
  for (int a = 0; a < 3; ++a)
    #pragma unroll
    for (int c = 0; c < 5; ++c){ float s = 0.f;
      #pragma unroll
      for (int b = 0; b < 3; ++b) s += cg[80 + (a*3 + b)*5 + c] * Y1v[b];
      B6[a*5 + c] = s; }
  #pragma unroll
  for (int a = 0; a < 3; ++a)
    #pragma unroll
    for (int c = 0; c < 3; ++c){ float s = 0.f;
      #pragma unroll
      for (int b = 0; b < 5; ++b) s += cg[125 + (a*5 + b)*3 + c] * Y2v[b];
      B7[a*3 + c] = s; }
  #pragma unroll
  for (int a = 0; a < 3; ++a)
    #pragma unroll
    for (int c = 0; c < 5; ++c){ float s = 0.f;
      #pragma unroll
      for (int b = 0; b < 5; ++b) s += cg[170 + (a*5 + b)*5 + c] * Y2v[b];
      B8[a*5 + c] = s; }

  int src = ei[2*e];
  const float* xr = nf + (size_t)src * 128;
  float* orow = out + (size_t)(d < 0 ? 0 : d) * 288;

  // ---- channel loop, tiled by 4 (x4 W2 loads, h1 from LDS) ----
  #pragma unroll 1
  for (int u4 = 0; u4 < 8; ++u4){
    v4f wv[9];
    #pragma unroll
    for (int p = 0; p < 9; ++p) wv[p] = (v4f)(0.f);
    #pragma unroll 4
    for (int k = 0; k < 64; ++k){
      float hk = h1s[k * TPB + tid];
      const v4f* w2r = (const v4f*)(W2 + k * 288 + 4 * u4);
      #pragma unroll
      for (int p = 0; p < 9; ++p){
        v4f w = w2r[p * 8];          // p*32 floats
        wv[p] += hk * w;
      }
    }

    v4f x0v = *(const v4f*)(xr + 4 * u4);
    float xl[12];
    {
      const v4f* xp = (const v4f*)(xr + 32 + 12 * u4);
      *(v4f*)&xl[0] = xp[0];
      *(v4f*)&xl[4] = xp[1];
      *(v4f*)&xl[8] = xp[2];
    }

    #pragma unroll
    for (int j = 0; j < 4; ++j){
      int u = 4 * u4 + j;
      float wvj[9];
      #pragma unroll
      for (int p = 0; p < 9; ++p) wvj[p] = silu_f(wv[p][j]);

      float x0 = x0v[j];
      float xa = xl[3*j + 0], xb = xl[3*j + 1], xc = xl[3*j + 2];

      float a0 = wvj[0] * (B0 * x0)
               + wvj[4] * (B4[0]*xa + B4[1]*xb + B4[2]*xc);
      float a1[3];
      #pragma unroll
      for (int c = 0; c < 3; ++c)
        a1[c] = wvj[1] * (B1[c] * x0)
              + wvj[3] * (B3[c]*xa + B3[3+c]*xb + B3[6+c]*xc)
              + wvj[5] * (B5[c]*xa + B5[3+c]*xb + B5[6+c]*xc)
              + wvj[7] * (B7[c]*xa + B7[3+c]*xb + B7[6+c]*xc);
      float a2[5];
      #pragma unroll
      for (int c = 0; c < 5; ++c)
        a2[c] = wvj[2] * (B2[c] * x0)
              + wvj[6] * (B6[c]*xa + B6[5+c]*xb + B6[10+c]*xc)
              + wvj[8] * (B8[c]*xa + B8[5+c]*xb + B8[10+c]*xc);

      SEGSUM(a0);
      #pragma unroll
      for (int c = 0; c < 3; ++c) SEGSUM(a1[c]);
      #pragma unroll
      for (int c = 0; c < 5; ++c) SEGSUM(a2[c]);

      if (tail){
        unsafeAtomicAdd(&orow[u], a0);
        #pragma unroll
        for (int c = 0; c < 3; ++c) unsafeAtomicAdd(&orow[32 + 3*u + c], a1[c]);
        #pragma unroll
        for (int c = 0; c < 5; ++c) unsafeAtomicAdd(&orow[128 + 5*u + c], a2[c]);
      }
    }
  }
}

// fallback (atomic per edge) if ws too small for CSR arrays
__global__ void __launch_bounds__(TPB, 2) tfn_atomic_kernel(
    const float* __restrict__ nf, const float* __restrict__ ef,
    const float* __restrict__ ev, const int* __restrict__ ei,
    const float* __restrict__ W0, const float* __restrict__ W1,
    const float* __restrict__ W2, const float* __restrict__ cg,
    float* __restrict__ out, int E)
{
  int e = blockIdx.x * TPB + threadIdx.x;
  if (e >= E) return;

  float f0[16];
  #pragma unroll
  for (int q = 0; q < 16; ++q) f0[q] = ef[(size_t)e*16 + q];
  float h1[64];
  #pragma unroll
  for (int j = 0; j < 64; ++j) h1[j] = 0.f;
  for (int k = 0; k < 64; ++k){
    float a = 0.f;
    #pragma unroll
    for (int q = 0; q < 16; ++q) a += f0[q] * W0[q*64 + k];
    float g = silu_f(a);
    #pragma unroll
    for (int j = 0; j < 64; ++j) h1[j] += g * W1[k*64 + j];
  }
  #pragma unroll
  for (int j = 0; j < 64; ++j) h1[j] = silu_f(h1[j]);

  float ex = ev[(size_t)e*3+0], eyv = ev[(size_t)e*3+1], ezv = ev[(size_t)e*3+2];
  float ri = __builtin_amdgcn_rcpf(sqrtf(ex*ex + eyv*eyv + ezv*ezv) + 1e-12f);
  float X = ex*ri, Y = eyv*ri, Z = ezv*ri;
  const float s3 = 1.7320508075688772f;
  float Y1v[3] = {Y, Z, X};
  float Y2v[5] = {s3*X*Y, s3*Y*Z, 0.5f*(3.f*Z*Z - 1.f), s3*X*Z, 0.5f*s3*(X*X - Y*Y)};

  float B0 = cg[0];
  float B1[3], B2[5], B3[9], B4[3], B5[9], B6[15], B7[9], B8[15];
  #pragma unroll
  for (int c = 0; c < 3; ++c){ float s = 0.f;
    #pragma unroll
    for (int b = 0; b < 3; ++b) s += cg[1 + b*3 + c] * Y1v[b];
    B1[c] = s; }
  #pragma unroll
  for (int c = 0; c < 5; ++c){ float s = 0.f;
    #pragma unroll
    for (int b = 0; b < 5; ++b) s += cg[10 + b*5 + c] * Y2v[b];
    B2[c] = s; }
  #pragma unroll
  for (int i = 0; i < 9; ++i) B3[i] = cg[35 + i];
  #pragma unroll
  for (int a = 0; a < 3; ++a){ float s = 0.f;
    #pragma unroll
    for (int b = 0; b < 3; ++b) s += cg[44 + a*3 + b] * Y1v[b];
    B4[a] = s; }
  #pragma unroll
  for (int a = 0; a < 3; ++a)
    #pragma unroll
    for (int c = 0; c < 3; ++c){ float s = 0.f;
      #pragma unroll
      for (int b = 0; b < 3; ++b) s += cg[53 + (a*3 + b)*3 + c] * Y1v[b];
      B5[a*3 + c] = s; }
  #pragma unroll
  for (int a = 0; a < 3; ++a)
    #pragma unroll
    for (int c = 0; c < 5; ++c){ float s = 0.f;
      #pragma unroll
      for (int b = 0; b < 3; ++b) s += cg[80 + (a*3 + b)*5 + c] * Y1v[b];
      B6[a*5 + c] = s; }
  #pragma unroll
  for (int a = 0; a < 3; ++a)
    #pragma unroll
    for (int c = 0; c < 3; ++c){ float s = 0.f;
      #pragma unroll
      for (int b = 0; b < 5; ++b) s += cg[125 + (a*5 + b)*3 + c] * Y2v[b];
      B7[a*3 + c] = s; }
  #pragma unroll
  for (int a = 0; a < 3; ++a)
    #pragma unroll
    for (int c = 0; c < 5; ++c){ float s = 0.f;
      #pragma unroll
      for (int b = 0; b < 5; ++b) s += cg[170 + (a*5 + b)*5 + c] * Y2v[b];
      B8[a*5 + c] = s; }

  int src = ei[2*e], dst = ei[2*e + 1];
  const float* xr = nf + (size_t)src * 128;
  float* orow = out + (size_t)dst * 288;

  for (int u = 0; u < 32; ++u){
    float wv[9];
    #pragma unroll
    for (int p = 0; p < 9; ++p) wv[p] = 0.f;
    #pragma unroll
    for (int k = 0; k < 64; ++k){
      float hk = h1[k];
      #pragma unroll
      for (int p = 0; p < 9; ++p) wv[p] += hk * W2[k*288 + p*32 + u];
    }
    #pragma unroll
    for (int p = 0; p < 9; ++p) wv[p] = silu_f(wv[p]);

    float x0 = xr[u];
    float xa = xr[32 + 3*u + 0], xb = xr[32 + 3*u + 1], xc = xr[32 + 3*u + 2];

    float a0 = wv[0] * (B0 * x0)
             + wv[4] * (B4[0]*xa + B4[1]*xb + B4[2]*xc);
    float a1[3];
    #pragma unroll
    for (int c = 0; c < 3; ++c)
      a1[c] = wv[1] * (B1[c] * x0)
            + wv[3] * (B3[c]*xa + B3[3+c]*xb + B3[6+c]*xc)
            + wv[5] * (B5[c]*xa + B5[3+c]*xb + B5[6+c]*xc)
            + wv[7] * (B7[c]*xa + B7[3+c]*xb + B7[6+c]*xc);
    float a2[5];
    #pragma unroll
    for (int c = 0; c < 5; ++c)
      a2[c] = wv[2] * (B2[c] * x0)
            + wv[6] * (B6[c]*xa + B6[5+c]*xb + B6[10+c]*xc)
            + wv[8] * (B8[c]*xa + B8[5+c]*xb + B8[10+c]*xc);

    unsafeAtomicAdd(&orow[u], a0);
    #pragma unroll
    for (int c = 0; c < 3; ++c) unsafeAtomicAdd(&orow[32 + 3*u + c], a1[c]);
    #pragma unroll
    for (int c = 0; c < 5; ++c) unsafeAtomicAdd(&orow[128 + 5*u + c], a2[c]);
  }
}

extern "C" void kernel_launch(void* const* d_in, const int* in_sizes, int n_in,
                              void* d_out, int out_size, void* d_ws, size_t ws_size,
                              hipStream_t stream)
{
  const float* nf = (const float*)d_in[0];
  const float* ef = (const float*)d_in[1];
  const float* ev = (const float*)d_in[2];
  const int*   ei = (const int*)  d_in[3];
  const float* W0 = (const float*)d_in[4];
  const float* W1 = (const float*)d_in[5];
  const float* W2 = (const float*)d_in[6];
  float* out = (float*)d_out;

  int E = in_sizes[3] / 2;
  int N = in_sizes[0] / 128;

  float* cg     = (float*)d_ws;                       // 256
  int*   counts = (int*)d_ws + 256;                   // N
  int*   starts = counts + N;                         // N+1
  int*   cursor = starts + N + 1;                     // N
  int*   perm   = cursor + N;                         // E
  size_t need_bytes = (size_t)(256 + 3*N + 1 + E) * 4;

  cg_init_kernel<<<1, 256, 0, stream>>>(cg);
  hipMemsetAsync(d_out, 0, (size_t)out_size * sizeof(float), stream);

  if (ws_size >= need_bytes){
    hipMemsetAsync(counts, 0, (size_t)N * sizeof(int), stream);
    hist_kernel<<<(E + TPB - 1) / TPB, TPB, 0, stream>>>(ei, counts, E);
    scan_kernel<<<1, 1024, 0, stream>>>(counts, starts, cursor, N);
    perm_kernel<<<(E + TPB - 1) / TPB, TPB, 0, stream>>>(ei, cursor, perm, E);
    tfn_sorted_kernel<<<(E + TPB - 1) / TPB, TPB, 0, stream>>>(nf, ef, ev, ei, W0, W1, W2, cg, perm, out, E);
  } else {
    tfn_atomic_kernel<<<(E + TPB - 1) / TPB, TPB, 0, stream>>>(nf, ef, ev, ei, W0, W1, W2, cg, out, E);
  }
}

// Round 6
// 706.524 us; speedup vs baseline: 6.3524x; 2.9382x over previous
//
#include <hip/hip_runtime.h>
#include <hip/hip_bf16.h>
#include <math.h>

#define TPB 256
#define TE  64

typedef float  v4f __attribute__((ext_vector_type(4)));
typedef short  s8v __attribute__((ext_vector_type(8)));
typedef float  f4v __attribute__((ext_vector_type(4)));

// ---------------------------------------------------------------------------
// ws layout (4-byte units): cg[256] | counts[N] | starts[N+1] | cursor[N] | perm[E]
// ---------------------------------------------------------------------------

__device__ double dfact(int n){ double r = 1.0; for (int i = 2; i <= n; ++i) r *= (double)i; return r; }

__device__ void build_u(int l, double ur[5][5], double ui[5][5]){
  for (int i = 0; i < 5; ++i) for (int j = 0; j < 5; ++j){ ur[i][j] = 0.0; ui[i][j] = 0.0; }
  ur[l][l] = 1.0;
  double s = 1.0 / sqrt(2.0);
  for (int m = 1; m <= l; ++m){
    double sg = (m & 1) ? -1.0 : 1.0;
    ur[l + m][l + m] = sg * s;
    ur[l + m][l - m] = s;
    ui[l - m][l - m] = s;
    ui[l - m][l + m] = -sg * s;
  }
}

// One thread per CG output element (245). Re/im choice = parity rule.
__global__ void cg_init_kernel(float* __restrict__ cg){
  int tid = threadIdx.x;
  if (tid >= 245) return;
  const int L1[9]  = {0,0,0,1,1,1,1,1,1};
  const int L2[9]  = {0,1,2,0,1,1,1,2,2};
  const int L3[9]  = {0,1,2,1,0,1,2,1,2};
  const int OFF[10] = {0,1,10,35,44,53,80,125,170,245};
  int p = 0;
  while (p < 8 && tid >= OFF[p+1]) ++p;
  int idx = tid - OFF[p];
  int l1 = L1[p], l2 = L2[p], l3 = L3[p];
  int n1 = 2*l1+1, n2 = 2*l2+1, n3 = 2*l3+1;
  int c = idx % n3; int ab = idx / n3; int b = ab % n2; int a = ab / n2;

  double Cc[5][5][5];
  for (int i = 0; i < 5; ++i) for (int j = 0; j < 5; ++j) for (int k = 0; k < 5; ++k) Cc[i][j][k] = 0.0;
  for (int m1 = -l1; m1 <= l1; ++m1) for (int m2 = -l2; m2 <= l2; ++m2){
    int m3 = m1 + m2;
    if (m3 < -l3 || m3 > l3) continue;
    double pref = sqrt((double)(2*l3+1) * dfact(l1+l2-l3) * dfact(l1-l2+l3) * dfact(-l1+l2+l3) / dfact(l1+l2+l3+1));
    pref *= sqrt(dfact(l3+m3)*dfact(l3-m3)*dfact(l1-m1)*dfact(l1+m1)*dfact(l2-m2)*dfact(l2+m2));
    double s = 0.0;
    for (int k = 0; k <= l1 + l2 - l3; ++k){
      int a0 = k, a1 = l1+l2-l3-k, a2 = l1-m1-k, a3 = l2+m2-k, a4 = l3-l2+m1+k, a5 = l3-l1-m2+k;
      if (a0 < 0 || a1 < 0 || a2 < 0 || a3 < 0 || a4 < 0 || a5 < 0) continue;
      double dd = dfact(a0)*dfact(a1)*dfact(a2)*dfact(a3)*dfact(a4)*dfact(a5);
      s += ((k & 1) ? -1.0 : 1.0) / dd;
    }
    Cc[m1+l1][m2+l2][m3+l3] = pref * s;
  }

  double U1r[5][5], U1i[5][5], U2r[5][5], U2i[5][5], U3r[5][5], U3i[5][5];
  build_u(l1, U1r, U1i); build_u(l2, U2r, U2i); build_u(l3, U3r, U3i);

  double sr = 0.0, si = 0.0;
  for (int m = 0; m < n1; ++m) for (int n = 0; n < n2; ++n) for (int o = 0; o < n3; ++o){
    double cc = Cc[m][n][o];
    if (cc == 0.0) continue;
    double xre = U1r[a][m], xim = U1i[a][m];
    double yre = U2r[b][n], yim = U2i[b][n];
    double zr = xre*yre - xim*yim, zi = xre*yim + xim*yre;
    double wr = U3r[c][o], wi = -U3i[c][o];
    double pr = zr*wr - zi*wi, pi = zr*wi + zi*wr;
    sr += pr * cc; si += pi * cc;
  }
  int use_re = (((l1 + l2 + l3) & 1) == 0);
  cg[tid] = (float)(use_re ? sr : si);
}

// ---------------- CSR build ----------------

__global__ void hist_kernel(const int* __restrict__ ei, int* __restrict__ counts, int E){
  int e = blockIdx.x * TPB + threadIdx.x;
  if (e < E) atomicAdd(&counts[ei[2*e + 1]], 1);
}

__global__ void scan_kernel(const int* __restrict__ counts, int* __restrict__ starts,
                            int* __restrict__ cursor, int N){
  __shared__ int part[1024];
  int t = threadIdx.x;
  int T = (N + 1023) >> 10;
  int base = t * T;
  int s = 0;
  for (int i = 0; i < T; ++i){ int idx = base + i; if (idx < N) s += counts[idx]; }
  part[t] = s; __syncthreads();
  for (int off = 1; off < 1024; off <<= 1){
    int v = (t >= off) ? part[t - off] : 0;
    __syncthreads();
    part[t] += v;
    __syncthreads();
  }
  int excl = (t == 0) ? 0 : part[t - 1];
  for (int i = 0; i < T; ++i){
    int idx = base + i;
    if (idx < N){ starts[idx] = excl; cursor[idx] = excl; excl += counts[idx]; }
  }
  if (t == 1023) starts[N] = part[1023];
}

__global__ void perm_kernel(const int* __restrict__ ei, int* __restrict__ cursor,
                            int* __restrict__ perm, int E){
  int e = blockIdx.x * TPB + threadIdx.x;
  if (e < E){
    int pos = atomicAdd(&cursor[ei[2*e + 1]], 1);
    perm[pos] = e;
  }
}

// ---------------- helpers ----------------

__device__ __forceinline__ float silu_f(float x){
  float t = __expf(-x);
  return x * __builtin_amdgcn_rcpf(1.0f + t);
}

__device__ __forceinline__ ushort f2bf(float x){
  __hip_bfloat16 h = __float2bfloat16(x);   // RNE
  return *reinterpret_cast<ushort*>(&h);
}

#define SEGSUM(v) { float _o; \
  _o = __shfl_up(v, 1);  v += samef[0]*_o; \
  _o = __shfl_up(v, 2);  v += samef[1]*_o; \
  _o = __shfl_up(v, 4);  v += samef[2]*_o; \
  _o = __shfl_up(v, 8);  v += samef[3]*_o; \
  _o = __shfl_up(v, 16); v += samef[4]*_o; \
  _o = __shfl_up(v, 32); v += samef[5]*_o; }

// ---------------------------------------------------------------------------
// Block-cooperative kernel: 256 threads / 64 dst-sorted edges.
//  P1: per-thread MLP (edge=tid&63, j-quarter=tid>>6) -> Hs bf16 [64e][64k]+pad
//  P2: stage W2^T half (9 paths x 16 u x 64 k) bf16 -> W2h [144][64k]+pad
//  P3: per-wave MFMA 16x16x32_bf16: row-tile=wave, 9 col-tiles x 2 k -> Cs f32
//  P4: lane=edge, wave owns 4 u: silu + tensor + SEGSUM + tail atomics
// Two u-halves reuse W2h/Cs. LDS = 9216+20736+38144 = 68096 B -> 2 blocks/CU.
// ---------------------------------------------------------------------------
__global__ void __launch_bounds__(TPB, 2) tfn_mfma_kernel(
    const float* __restrict__ nf, const float* __restrict__ ef,
    const float* __restrict__ ev, const int* __restrict__ ei,
    const float* __restrict__ W0, const float* __restrict__ W1,
    const float* __restrict__ W2, const float* __restrict__ cg,
    const int* __restrict__ perm, float* __restrict__ out, int E)
{
  __shared__ ushort Hs[TE * 72];       // [edge][k], pad 72
  __shared__ ushort W2h[144 * 72];     // [p*16+c][k], pad 72
  __shared__ float  Cs[TE * 149];      // [edge][p*16+uu], pad 149

  const int tid  = threadIdx.x;
  const int el   = tid & 63;           // edge lane (== hw lane)
  const int wq   = tid >> 6;           // wave id 0..3
  const int lane = el;

  int t = blockIdx.x * TE + el;
  bool valid = (t < E);
  int e = perm[valid ? t : (E - 1)];
  int d = valid ? ei[2*e + 1] : -1;
  int src = ei[2*e];

  // segment predicates (dst non-decreasing along lanes; same in every wave)
  float samef[6];
  #pragma unroll
  for (int s = 0; s < 6; ++s){
    int off = 1 << s;
    int od = __shfl_up(d, off);
    samef[s] = (lane >= off && od == d) ? 1.0f : 0.0f;
  }
  int nd = __shfl_down(d, 1);
  bool tail = valid && ((lane == 63) || (nd != d));

  // ================= Phase 1: MLP layers 0+1 (j-quarter per thread) ========
  {
    float f0[16];
    const v4f* efv = (const v4f*)(ef + (size_t)e * 16);
    *(v4f*)&f0[0]  = efv[0];
    *(v4f*)&f0[4]  = efv[1];
    *(v4f*)&f0[8]  = efv[2];
    *(v4f*)&f0[12] = efv[3];

    float acc[64];
    #pragma unroll
    for (int j = 0; j < 64; ++j) acc[j] = 0.f;
    #pragma unroll
    for (int q = 0; q < 16; ++q){
      float fq = f0[q];
      const v4f* w0r = (const v4f*)(W0 + q * 64);
      #pragma unroll
      for (int k4 = 0; k4 < 16; ++k4){
        v4f w = w0r[k4];
        acc[4*k4+0] += fq * w.x; acc[4*k4+1] += fq * w.y;
        acc[4*k4+2] += fq * w.z; acc[4*k4+3] += fq * w.w;
      }
    }
    #pragma unroll
    for (int j = 0; j < 64; ++j) acc[j] = silu_f(acc[j]);

    float a1q[16];
    #pragma unroll
    for (int j = 0; j < 16; ++j) a1q[j] = 0.f;
    for (int k = 0; k < 64; ++k){
      float g = acc[k];
      const v4f* w1r = (const v4f*)(W1 + k * 64 + wq * 16);
      #pragma unroll
      for (int j4 = 0; j4 < 4; ++j4){
        v4f w = w1r[j4];
        a1q[4*j4+0] += g * w.x; a1q[4*j4+1] += g * w.y;
        a1q[4*j4+2] += g * w.z; a1q[4*j4+3] += g * w.w;
      }
    }
    #pragma unroll
    for (int j2 = 0; j2 < 8; ++j2){
      uint pk = (uint)f2bf(silu_f(a1q[2*j2])) | ((uint)f2bf(silu_f(a1q[2*j2+1])) << 16);
      *(uint*)&Hs[el * 72 + wq * 16 + 2*j2] = pk;
    }
  }

  // ---- stage W2^T half 0 ----
  #pragma unroll 1
  for (int m = 0; m < 36; ++m){
    int flat = m * TPB + tid;
    int col  = flat % 144;
    int k    = flat / 144;
    int n    = (col >> 4) * 32 + (col & 15);       // half 0
    W2h[col * 72 + k] = f2bf(W2[k * 288 + n]);
  }

  // ---- spherical harmonics + Y-contracted CG (register-resident) ----
  float ex = ev[(size_t)e*3+0], eyv = ev[(size_t)e*3+1], ezv = ev[(size_t)e*3+2];
  float ri = __builtin_amdgcn_rcpf(sqrtf(ex*ex + eyv*eyv + ezv*ezv) + 1e-12f);
  float X = ex*ri, Y = eyv*ri, Z = ezv*ri;
  const float s3 = 1.7320508075688772f;
  float Y1v[3] = {Y, Z, X};
  float Y2v[5] = {s3*X*Y, s3*Y*Z, 0.5f*(3.f*Z*Z - 1.f), s3*X*Z, 0.5f*s3*(X*X - Y*Y)};

  float B0 = cg[0];
  float B1[3], B2[5], B3[9], B4[3], B5[9], B6[15], B7[9], B8[15];
  #pragma unroll
  for (int c = 0; c < 3; ++c){ float s = 0.f;
    #pragma unroll
    for (int b = 0; b < 3; ++b) s += cg[1 + b*3 + c] * Y1v[b];
    B1[c] = s; }
  #pragma unroll
  for (int c = 0; c < 5; ++c){ float s = 0.f;
    #pragma unroll
    for (int b = 0; b < 5; ++b) s += cg[10 + b*5 + c] * Y2v[b];
    B2[c] = s; }
  #pragma unroll
  for (int i = 0; i < 9; ++i) B3[i] = cg[35 + i];
  #pragma unroll
  for (int a = 0; a < 3; ++a){ float s = 0.f;
    #pragma unroll
    for (int b = 0; b < 3; ++b) s += cg[44 + a*3 + b] * Y1v[b];
    B4[a] = s; }
  #pragma unroll
  for (int a = 0; a < 3; ++a)
    #pragma unroll
    for (int c = 0; c < 3; ++c){ float s = 0.f;
      #pragma unroll
      for (int b = 0; b < 3; ++b) s += cg[53 + (a*3 + b)*3 + c] * Y1v[b];
      B5[a*3 + c] = s; }
  #pragma unroll
  for (int a = 0; a < 3; ++a)
    #pragma unroll
    for (int c = 0; c < 5; ++c){ float s = 0.f;
      #pragma unroll
      for (int b = 0; b < 3; ++b) s += cg[80 + (a*3 + b)*5 + c] * Y1v[b];
      B6[a*5 + c] = s; }
  #pragma unroll
  for (int a = 0; a < 3; ++a)
    #pragma unroll
    for (int c = 0; c < 3; ++c){ float s = 0.f;
      #pragma unroll
      for (int b = 0; b < 5; ++b) s += cg[125 + (a*5 + b)*3 + c] * Y2v[b];
      B7[a*3 + c] = s; }
  #pragma unroll
  for (int a = 0; a < 3; ++a)
    #pragma unroll
    for (int c = 0; c < 5; ++c){ float s = 0.f;
      #pragma unroll
      for (int b = 0; b < 5; ++b) s += cg[170 + (a*5 + b)*5 + c] * Y2v[b];
      B8[a*5 + c] = s; }

  const float* xr = nf + (size_t)src * 128;
  float* orow = out + (size_t)(d < 0 ? 0 : d) * 288;

  const int r = lane & 15, q = lane >> 4;
  const int rowbase = wq * 16;

  #pragma unroll 1
  for (int h = 0; h < 2; ++h){
    __syncthreads();   // Hs+W2h ready (h=0) / Cs consumed + W2h restaged (h=1)

    // ============== Phase 3: MFMA ==============
    #pragma unroll 1
    for (int p = 0; p < 9; ++p){
      f4v acc4 = {0.f, 0.f, 0.f, 0.f};
      #pragma unroll
      for (int ks = 0; ks < 2; ++ks){
        s8v a = *(const s8v*)&Hs[(rowbase + r) * 72 + ks*32 + q*8];
        s8v b = *(const s8v*)&W2h[(p*16 + r) * 72 + ks*32 + q*8];
        acc4 = __builtin_amdgcn_mfma_f32_16x16x32_bf16(a, b, acc4, 0, 0, 0);
      }
      #pragma unroll
      for (int rr = 0; rr < 4; ++rr)
        Cs[(rowbase + q*4 + rr) * 149 + p*16 + r] = acc4[rr];
    }

    __syncthreads();   // Cs ready

    // ============== Phase 4: silu + tensor + segmented scatter ==============
    #pragma unroll 1
    for (int j = 0; j < 4; ++j){
      int uu = wq * 4 + j;
      int u  = h * 16 + uu;

      float wvj[9];
      #pragma unroll
      for (int p = 0; p < 9; ++p) wvj[p] = silu_f(Cs[el * 149 + p*16 + uu]);

      float x0 = xr[u];
      float xa = xr[32 + 3*u + 0], xb = xr[32 + 3*u + 1], xc = xr[32 + 3*u + 2];

      float a0 = wvj[0] * (B0 * x0)
               + wvj[4] * (B4[0]*xa + B4[1]*xb + B4[2]*xc);
      float a1[3];
      #pragma unroll
      for (int c = 0; c < 3; ++c)
        a1[c] = wvj[1] * (B1[c] * x0)
              + wvj[3] * (B3[c]*xa + B3[3+c]*xb + B3[6+c]*xc)
              + wvj[5] * (B5[c]*xa + B5[3+c]*xb + B5[6+c]*xc)
              + wvj[7] * (B7[c]*xa + B7[3+c]*xb + B7[6+c]*xc);
      float a2[5];
      #pragma unroll
      for (int c = 0; c < 5; ++c)
        a2[c] = wvj[2] * (B2[c] * x0)
              + wvj[6] * (B6[c]*xa + B6[5+c]*xb + B6[10+c]*xc)
              + wvj[8] * (B8[c]*xa + B8[5+c]*xb + B8[10+c]*xc);

      SEGSUM(a0);
      #pragma unroll
      for (int c = 0; c < 3; ++c) SEGSUM(a1[c]);
      #pragma unroll
      for (int c = 0; c < 5; ++c) SEGSUM(a2[c]);

      if (tail){
        unsafeAtomicAdd(&orow[u], a0);
        #pragma unroll
        for (int c = 0; c < 3; ++c) unsafeAtomicAdd(&orow[32 + 3*u + c], a1[c]);
        #pragma unroll
        for (int c = 0; c < 5; ++c) unsafeAtomicAdd(&orow[128 + 5*u + c], a2[c]);
      }
    }

    // ---- stage W2^T half 1 (overlaps phase-4 epoch; W2h unread until next barrier) ----
    if (h == 0){
      #pragma unroll 1
      for (int m = 0; m < 36; ++m){
        int flat = m * TPB + tid;
        int col  = flat % 144;
        int k    = flat / 144;
        int n    = (col >> 4) * 32 + 16 + (col & 15);   // half 1
        W2h[col * 72 + k] = f2bf(W2[k * 288 + n]);
      }
    }
  }
}

// fallback (atomic per edge) if ws too small for CSR arrays
__global__ void __launch_bounds__(TPB, 2) tfn_atomic_kernel(
    const float* __restrict__ nf, const float* __restrict__ ef,
    const float* __restrict__ ev, const int* __restrict__ ei,
    const float* __restrict__ W0, const float* __restrict__ W1,
    const float* __restrict__ W2, const float* __restrict__ cg,
    float* __restrict__ out, int E)
{
  int e = blockIdx.x * TPB + threadIdx.x;
  if (e >= E) return;

  float f0[16];
  #pragma unroll
  for (int q = 0; q < 16; ++q) f0[q] = ef[(size_t)e*16 + q];
  float h1[64];
  #pragma unroll
  for (int j = 0; j < 64; ++j) h1[j] = 0.f;
  for (int k = 0; k < 64; ++k){
    float a = 0.f;
    #pragma unroll
    for (int q = 0; q < 16; ++q) a += f0[q] * W0[q*64 + k];
    float g = silu_f(a);
    #pragma unroll
    for (int j = 0; j < 64; ++j) h1[j] += g * W1[k*64 + j];
  }
  #pragma unroll
  for (int j = 0; j < 64; ++j) h1[j] = silu_f(h1[j]);

  float ex = ev[(size_t)e*3+0], eyv = ev[(size_t)e*3+1], ezv = ev[(size_t)e*3+2];
  float ri = __builtin_amdgcn_rcpf(sqrtf(ex*ex + eyv*eyv + ezv*ezv) + 1e-12f);
  float X = ex*ri, Y = eyv*ri, Z = ezv*ri;
  const float s3 = 1.7320508075688772f;
  float Y1v[3] = {Y, Z, X};
  float Y2v[5] = {s3*X*Y, s3*Y*Z, 0.5f*(3.f*Z*Z - 1.f), s3*X*Z, 0.5f*s3*(X*X - Y*Y)};

  float B0 = cg[0];
  float B1[3], B2[5], B3[9], B4[3], B5[9], B6[15], B7[9], B8[15];
  #pragma unroll
  for (int c = 0; c < 3; ++c){ float s = 0.f;
    #pragma unroll
    for (int b = 0; b < 3; ++b) s += cg[1 + b*3 + c] * Y1v[b];
    B1[c] = s; }
  #pragma unroll
  for (int c = 0; c < 5; ++c){ float s = 0.f;
    #pragma unroll
    for (int b = 0; b < 5; ++b) s += cg[10 + b*5 + c] * Y2v[b];
    B2[c] = s; }
  #pragma unroll
  for (int i = 0; i < 9; ++i) B3[i] = cg[35 + i];
  #pragma unroll
  for (int a = 0; a < 3; ++a){ float s = 0.f;
    #pragma unroll
    for (int b = 0; b < 3; ++b) s += cg[44 + a*3 + b] * Y1v[b];
    B4[a] = s; }
  #pragma unroll
  for (int a = 0; a < 3; ++a)
    #pragma unroll
    for (int c = 0; c < 3; ++c){ float s = 0.f;
      #pragma unroll
      for (int b = 0; b < 3; ++b) s += cg[53 + (a*3 + b)*3 + c] * Y1v[b];
      B5[a*3 + c] = s; }
  #pragma unroll
  for (int a = 0; a < 3; ++a)
    #pragma unroll
    for (int c = 0; c < 5; ++c){ float s = 0.f;
      #pragma unroll
      for (int b = 0; b < 3; ++b) s += cg[80 + (a*3 + b)*5 + c] * Y1v[b];
      B6[a*5 + c] = s; }
  #pragma unroll
  for (int a = 0; a < 3; ++a)
    #pragma unroll
    for (int c = 0; c < 3; ++c){ float s = 0.f;
      #pragma unroll
      for (int b = 0; b < 5; ++b) s += cg[125 + (a*5 + b)*3 + c] * Y2v[b];
      B7[a*3 + c] = s; }
  #pragma unroll
  for (int a = 0; a < 3; ++a)
    #pragma unroll
    for (int c = 0; c < 5; ++c){ float s = 0.f;
      #pragma unroll
      for (int b = 0; b < 5; ++b) s += cg[170 + (a*5 + b)*5 + c] * Y2v[b];
      B8[a*5 + c] = s; }

  int src = ei[2*e], dst = ei[2*e + 1];
  const float* xr = nf + (size_t)src * 128;
  float* orow = out + (size_t)dst * 288;

  for (int u = 0; u < 32; ++u){
    float wv[9];
    #pragma unroll
    for (int p = 0; p < 9; ++p) wv[p] = 0.f;
    #pragma unroll
    for (int k = 0; k < 64; ++k){
      float hk = h1[k];
      #pragma unroll
      for (int p = 0; p < 9; ++p) wv[p] += hk * W2[k*288 + p*32 + u];
    }
    #pragma unroll
    for (int p = 0; p < 9; ++p) wv[p] = silu_f(wv[p]);

    float x0 = xr[u];
    float xa = xr[32 + 3*u + 0], xb = xr[32 + 3*u + 1], xc = xr[32 + 3*u + 2];

    float a0 = wv[0] * (B0 * x0)
             + wv[4] * (B4[0]*xa + B4[1]*xb + B4[2]*xc);
    float a1[3];
    #pragma unroll
    for (int c = 0; c < 3; ++c)
      a1[c] = wv[1] * (B1[c] * x0)
            + wv[3] * (B3[c]*xa + B3[3+c]*xb + B3[6+c]*xc)
            + wv[5] * (B5[c]*xa + B5[3+c]*xb + B5[6+c]*xc)
            + wv[7] * (B7[c]*xa + B7[3+c]*xb + B7[6+c]*xc);
    float a2[5];
    #pragma unroll
    for (int c = 0; c < 5; ++c)
      a2[c] = wv[2] * (B2[c] * x0)
            + wv[6] * (B6[c]*xa + B6[5+c]*xb + B6[10+c]*xc)
            + wv[8] * (B8[c]*xa + B8[5+c]*xb + B8[10+c]*xc);

    unsafeAtomicAdd(&orow[u], a0);
    #pragma unroll
    for (int c = 0; c < 3; ++c) unsafeAtomicAdd(&orow[32 + 3*u + c], a1[c]);
    #pragma unroll
    for (int c = 0; c < 5; ++c) unsafeAtomicAdd(&orow[128 + 5*u + c], a2[c]);
  }
}

extern "C" void kernel_launch(void* const* d_in, const int* in_sizes, int n_in,
                              void* d_out, int out_size, void* d_ws, size_t ws_size,
                              hipStream_t stream)
{
  const float* nf = (const float*)d_in[0];
  const float* ef = (const float*)d_in[1];
  const float* ev = (const float*)d_in[2];
  const int*   ei = (const int*)  d_in[3];
  const float* W0 = (const float*)d_in[4];
  const float* W1 = (const float*)d_in[5];
  const float* W2 = (const float*)d_in[6];
  float* out = (float*)d_out;

  int E = in_sizes[3] / 2;
  int N = in_sizes[0] / 128;

  float* cg     = (float*)d_ws;                       // 256
  int*   counts = (int*)d_ws + 256;                   // N
  int*   starts = counts + N;                         // N+1
  int*   cursor = starts + N + 1;                     // N
  int*   perm   = cursor + N;                         // E
  size_t need_bytes = (size_t)(256 + 3*N + 1 + E) * 4;

  cg_init_kernel<<<1, 256, 0, stream>>>(cg);
  hipMemsetAsync(d_out, 0, (size_t)out_size * sizeof(float), stream);

  if (ws_size >= need_bytes){
    hipMemsetAsync(counts, 0, (size_t)N * sizeof(int), stream);
    hist_kernel<<<(E + TPB - 1) / TPB, TPB, 0, stream>>>(ei, counts, E);
    scan_kernel<<<1, 1024, 0, stream>>>(counts, starts, cursor, N);
    perm_kernel<<<(E + TPB - 1) / TPB, TPB, 0, stream>>>(ei, cursor, perm, E);
    tfn_mfma_kernel<<<(E + TE - 1) / TE, TPB, 0, stream>>>(nf, ef, ev, ei, W0, W1, W2, cg, perm, out, E);
  } else {
    tfn_atomic_kernel<<<(E + TPB - 1) / TPB, TPB, 0, stream>>>(nf, ef, ev, ei, W0, W1, W2, cg, out, E);
  }
}

// Round 7
// 623.254 us; speedup vs baseline: 7.2011x; 1.1336x over previous
//
#include <hip/hip_runtime.h>
#include <hip/hip_bf16.h>
#include <math.h>

#define TPB 256
#define TE  64

typedef float  v4f __attribute__((ext_vector_type(4)));
typedef short  s8v __attribute__((ext_vector_type(8)));
typedef float  f4v __attribute__((ext_vector_type(4)));

// ---------------------------------------------------------------------------
// ws layout (4-byte units):
//   cg[256] | counts[N] | starts[N+1] | cursor[N] | nzrank[N] | perm[E]
//   | rows_dst[R] | (align) rows[R*288]
// R = E/64 + N + 64. Rows indexed by ri = nzrank(dst) + position/64:
// unique per (dst,block-window), consecutive per dst, gaps carry rows_dst=-1.
// ---------------------------------------------------------------------------

__device__ double dfact(int n){ double r = 1.0; for (int i = 2; i <= n; ++i) r *= (double)i; return r; }

__device__ void build_u(int l, double ur[5][5], double ui[5][5]){
  for (int i = 0; i < 5; ++i) for (int j = 0; j < 5; ++j){ ur[i][j] = 0.0; ui[i][j] = 0.0; }
  ur[l][l] = 1.0;
  double s = 1.0 / sqrt(2.0);
  for (int m = 1; m <= l; ++m){
    double sg = (m & 1) ? -1.0 : 1.0;
    ur[l + m][l + m] = sg * s;
    ur[l + m][l - m] = s;
    ui[l - m][l - m] = s;
    ui[l - m][l + m] = -sg * s;
  }
}

// One thread per CG output element (245). Re/im choice = parity rule.
__device__ void cg_compute(int tid, float* __restrict__ cg){
  if (tid >= 245) return;
  const int L1[9]  = {0,0,0,1,1,1,1,1,1};
  const int L2[9]  = {0,1,2,0,1,1,1,2,2};
  const int L3[9]  = {0,1,2,1,0,1,2,1,2};
  const int OFF[10] = {0,1,10,35,44,53,80,125,170,245};
  int p = 0;
  while (p < 8 && tid >= OFF[p+1]) ++p;
  int idx = tid - OFF[p];
  int l1 = L1[p], l2 = L2[p], l3 = L3[p];
  int n1 = 2*l1+1, n2 = 2*l2+1, n3 = 2*l3+1;
  int c = idx % n3; int ab = idx / n3; int b = ab % n2; int a = ab / n2;

  double Cc[5][5][5];
  for (int i = 0; i < 5; ++i) for (int j = 0; j < 5; ++j) for (int k = 0; k < 5; ++k) Cc[i][j][k] = 0.0;
  for (int m1 = -l1; m1 <= l1; ++m1) for (int m2 = -l2; m2 <= l2; ++m2){
    int m3 = m1 + m2;
    if (m3 < -l3 || m3 > l3) continue;
    double pref = sqrt((double)(2*l3+1) * dfact(l1+l2-l3) * dfact(l1-l2+l3) * dfact(-l1+l2+l3) / dfact(l1+l2+l3+1));
    pref *= sqrt(dfact(l3+m3)*dfact(l3-m3)*dfact(l1-m1)*dfact(l1+m1)*dfact(l2-m2)*dfact(l2+m2));
    double s = 0.0;
    for (int k = 0; k <= l1 + l2 - l3; ++k){
      int a0 = k, a1 = l1+l2-l3-k, a2 = l1-m1-k, a3 = l2+m2-k, a4 = l3-l2+m1+k, a5 = l3-l1-m2+k;
      if (a0 < 0 || a1 < 0 || a2 < 0 || a3 < 0 || a4 < 0 || a5 < 0) continue;
      double dd = dfact(a0)*dfact(a1)*dfact(a2)*dfact(a3)*dfact(a4)*dfact(a5);
      s += ((k & 1) ? -1.0 : 1.0) / dd;
    }
    Cc[m1+l1][m2+l2][m3+l3] = pref * s;
  }

  double U1r[5][5], U1i[5][5], U2r[5][5], U2i[5][5], U3r[5][5], U3i[5][5];
  build_u(l1, U1r, U1i); build_u(l2, U2r, U2i); build_u(l3, U3r, U3i);

  double sr = 0.0, si = 0.0;
  for (int m = 0; m < n1; ++m) for (int n = 0; n < n2; ++n) for (int o = 0; o < n3; ++o){
    double cc = Cc[m][n][o];
    if (cc == 0.0) continue;
    double xre = U1r[a][m], xim = U1i[a][m];
    double yre = U2r[b][n], yim = U2i[b][n];
    double zr = xre*yre - xim*yim, zi = xre*yim + xim*yre;
    double wr = U3r[c][o], wi = -U3i[c][o];
    double pr = zr*wr - zi*wi, pi = zr*wi + zi*wr;
    sr += pr * cc; si += pi * cc;
  }
  int use_re = (((l1 + l2 + l3) & 1) == 0);
  cg[tid] = (float)(use_re ? sr : si);
}

__global__ void cg_init_kernel(float* __restrict__ cg){
  cg_compute(threadIdx.x, cg);
}

// ---------------- CSR build (hist fused with cg) ----------------

__global__ void hist_cg_kernel(const int* __restrict__ ei, int* __restrict__ counts,
                               int E, float* __restrict__ cg, int nb){
  if ((int)blockIdx.x == nb){
    cg_compute(threadIdx.x, cg);
    return;
  }
  int e = blockIdx.x * TPB + threadIdx.x;
  if (e < E) atomicAdd(&counts[ei[2*e + 1]], 1);
}

__global__ void scan_kernel(const int* __restrict__ counts, int* __restrict__ starts,
                            int* __restrict__ cursor, int* __restrict__ nzrank, int N){
  __shared__ int part[1024];
  __shared__ int pnz[1024];
  int t = threadIdx.x;
  int T = (N + 1023) >> 10;
  int base = t * T;
  int s = 0, z = 0;
  for (int i = 0; i < T; ++i){
    int idx = base + i;
    if (idx < N){ int cc = counts[idx]; s += cc; z += (cc > 0); }
  }
  part[t] = s; pnz[t] = z; __syncthreads();
  for (int off = 1; off < 1024; off <<= 1){
    int v = (t >= off) ? part[t - off] : 0;
    int w = (t >= off) ? pnz[t - off] : 0;
    __syncthreads();
    part[t] += v; pnz[t] += w;
    __syncthreads();
  }
  int excl = (t == 0) ? 0 : part[t - 1];
  int enz  = (t == 0) ? 0 : pnz[t - 1];
  for (int i = 0; i < T; ++i){
    int idx = base + i;
    if (idx < N){
      starts[idx] = excl; cursor[idx] = excl; nzrank[idx] = enz;
      int cc = counts[idx];
      excl += cc; enz += (cc > 0);
    }
  }
  if (t == 1023) starts[N] = part[1023];
}

__global__ void perm_kernel(const int* __restrict__ ei, int* __restrict__ cursor,
                            int* __restrict__ perm, int E){
  int e = blockIdx.x * TPB + threadIdx.x;
  if (e < E){
    int pos = atomicAdd(&cursor[ei[2*e + 1]], 1);
    perm[pos] = e;
  }
}

// ---------------- helpers ----------------

__device__ __forceinline__ float silu_f(float x){
  float t = __expf(-x);
  return x * __builtin_amdgcn_rcpf(1.0f + t);
}

__device__ __forceinline__ ushort f2bf(float x){
  __hip_bfloat16 h = __float2bfloat16(x);   // RNE
  return *reinterpret_cast<ushort*>(&h);
}

#define SEGSUM(v) { float _o; \
  _o = __shfl_up(v, 1);  v += samef[0]*_o; \
  _o = __shfl_up(v, 2);  v += samef[1]*_o; \
  _o = __shfl_up(v, 4);  v += samef[2]*_o; \
  _o = __shfl_up(v, 8);  v += samef[3]*_o; \
  _o = __shfl_up(v, 16); v += samef[4]*_o; \
  _o = __shfl_up(v, 32); v += samef[5]*_o; }

// ---------------------------------------------------------------------------
// Block-cooperative MFMA kernel (structure of R6).
// USE_ROWS=true: tails write segment partials to rows[] with PLAIN stores
// (L2-cached, write-back) instead of uncached 32-B atomic RMWs.
// ---------------------------------------------------------------------------
template<bool USE_ROWS>
__global__ void __launch_bounds__(TPB, 2) tfn_mfma_kernel(
    const float* __restrict__ nf, const float* __restrict__ ef,
    const float* __restrict__ ev, const int* __restrict__ ei,
    const float* __restrict__ W0, const float* __restrict__ W1,
    const float* __restrict__ W2, const float* __restrict__ cg,
    const int* __restrict__ perm, const int* __restrict__ nzrank,
    float* __restrict__ rows, int* __restrict__ rows_dst,
    float* __restrict__ out, int E)
{
  __shared__ ushort Hs[TE * 72];       // [edge][k], pad 72
  __shared__ ushort W2h[144 * 72];     // [p*16+c][k], pad 72
  __shared__ float  Cs[TE * 149];      // [edge][p*16+uu], pad 149

  const int tid  = threadIdx.x;
  const int el   = tid & 63;
  const int wq   = tid >> 6;
  const int lane = el;

  int t = blockIdx.x * TE + el;
  bool valid = (t < E);
  int e = perm[valid ? t : (E - 1)];
  int d = valid ? ei[2*e + 1] : -1;
  int src = ei[2*e];

  float samef[6];
  #pragma unroll
  for (int s = 0; s < 6; ++s){
    int off = 1 << s;
    int od = __shfl_up(d, off);
    samef[s] = (lane >= off && od == d) ? 1.0f : 0.0f;
  }
  int nd = __shfl_down(d, 1);
  bool tail = valid && ((lane == 63) || (nd != d));

  // row index for this position's segment partial (USE_ROWS path)
  int ri = 0;
  if (USE_ROWS){
    ri = (d >= 0 ? nzrank[d] : 0) + (t >> 6);
    if (tail) rows_dst[ri] = d;
  }

  // ================= Phase 1: MLP layers 0+1 (j-quarter per thread) ========
  {
    float f0[16];
    const v4f* efv = (const v4f*)(ef + (size_t)e * 16);
    *(v4f*)&f0[0]  = efv[0];
    *(v4f*)&f0[4]  = efv[1];
    *(v4f*)&f0[8]  = efv[2];
    *(v4f*)&f0[12] = efv[3];

    float acc[64];
    #pragma unroll
    for (int j = 0; j < 64; ++j) acc[j] = 0.f;
    #pragma unroll
    for (int q = 0; q < 16; ++q){
      float fq = f0[q];
      const v4f* w0r = (const v4f*)(W0 + q * 64);
      #pragma unroll
      for (int k4 = 0; k4 < 16; ++k4){
        v4f w = w0r[k4];
        acc[4*k4+0] += fq * w.x; acc[4*k4+1] += fq * w.y;
        acc[4*k4+2] += fq * w.z; acc[4*k4+3] += fq * w.w;
      }
    }
    #pragma unroll
    for (int j = 0; j < 64; ++j) acc[j] = silu_f(acc[j]);

    float a1q[16];
    #pragma unroll
    for (int j = 0; j < 16; ++j) a1q[j] = 0.f;
    for (int k = 0; k < 64; ++k){
      float g = acc[k];
      const v4f* w1r = (const v4f*)(W1 + k * 64 + wq * 16);
      #pragma unroll
      for (int j4 = 0; j4 < 4; ++j4){
        v4f w = w1r[j4];
        a1q[4*j4+0] += g * w.x; a1q[4*j4+1] += g * w.y;
        a1q[4*j4+2] += g * w.z; a1q[4*j4+3] += g * w.w;
      }
    }
    #pragma unroll
    for (int j2 = 0; j2 < 8; ++j2){
      uint pk = (uint)f2bf(silu_f(a1q[2*j2])) | ((uint)f2bf(silu_f(a1q[2*j2+1])) << 16);
      *(uint*)&Hs[el * 72 + wq * 16 + 2*j2] = pk;
    }
  }

  // ---- stage W2^T half 0 ----
  #pragma unroll 1
  for (int m = 0; m < 36; ++m){
    int flat = m * TPB + tid;
    int col  = flat % 144;
    int k    = flat / 144;
    int n    = (col >> 4) * 32 + (col & 15);
    W2h[col * 72 + k] = f2bf(W2[k * 288 + n]);
  }

  // ---- spherical harmonics + Y-contracted CG ----
  float ex = ev[(size_t)e*3+0], eyv = ev[(size_t)e*3+1], ezv = ev[(size_t)e*3+2];
  float ri2 = __builtin_amdgcn_rcpf(sqrtf(ex*ex + eyv*eyv + ezv*ezv) + 1e-12f);
  float X = ex*ri2, Y = eyv*ri2, Z = ezv*ri2;
  const float s3 = 1.7320508075688772f;
  float Y1v[3] = {Y, Z, X};
  float Y2v[5] = {s3*X*Y, s3*Y*Z, 0.5f*(3.f*Z*Z - 1.f), s3*X*Z, 0.5f*s3*(X*X - Y*Y)};

  float B0 = cg[0];
  float B1[3], B2[5], B3[9], B4[3], B5[9], B6[15], B7[9], B8[15];
  #pragma unroll
  for (int c = 0; c < 3; ++c){ float s = 0.f;
    #pragma unroll
    for (int b = 0; b < 3; ++b) s += cg[1 + b*3 + c] * Y1v[b];
    B1[c] = s; }
  #pragma unroll
  for (int c = 0; c < 5; ++c){ float s = 0.f;
    #pragma unroll
    for (int b = 0; b < 5; ++b) s += cg[10 + b*5 + c] * Y2v[b];
    B2[c] = s; }
  #pragma unroll
  for (int i = 0; i < 9; ++i) B3[i] = cg[35 + i];
  #pragma unroll
  for (int a = 0; a < 3; ++a){ float s = 0.f;
    #pragma unroll
    for (int b = 0; b < 3; ++b) s += cg[44 + a*3 + b] * Y1v[b];
    B4[a] = s; }
  #pragma unroll
  for (int a = 0; a < 3; ++a)
    #pragma unroll
    for (int c = 0; c < 3; ++c){ float s = 0.f;
      #pragma unroll
      for (int b = 0; b < 3; ++b) s += cg[53 + (a*3 + b)*3 + c] * Y1v[b];
      B5[a*3 + c] = s; }
  #pragma unroll
  for (int a = 0; a < 3; ++a)
    #pragma unroll
    for (int c = 0; c < 5; ++c){ float s = 0.f;
      #pragma unroll
      for (int b = 0; b < 3; ++b) s += cg[80 + (a*3 + b)*5 + c] * Y1v[b];
      B6[a*5 + c] = s; }
  #pragma unroll
  for (int a = 0; a < 3; ++a)
    #pragma unroll
    for (int c = 0; c < 3; ++c){ float s = 0.f;
      #pragma unroll
      for (int b = 0; b < 5; ++b) s += cg[125 + (a*5 + b)*3 + c] * Y2v[b];
      B7[a*3 + c] = s; }
  #pragma unroll
  for (int a = 0; a < 3; ++a)
    #pragma unroll
    for (int c = 0; c < 5; ++c){ float s = 0.f;
      #pragma unroll
      for (int b = 0; b < 5; ++b) s += cg[170 + (a*5 + b)*5 + c] * Y2v[b];
      B8[a*5 + c] = s; }

  const float* xr = nf + (size_t)src * 128;
  float* dstrow = USE_ROWS ? (rows + (size_t)ri * 288)
                           : (out + (size_t)(d < 0 ? 0 : d) * 288);

  const int r = lane & 15, q = lane >> 4;
  const int rowbase = wq * 16;

  #pragma unroll 1
  for (int h = 0; h < 2; ++h){
    __syncthreads();

    // ============== Phase 3: MFMA ==============
    #pragma unroll 1
    for (int p = 0; p < 9; ++p){
      f4v acc4 = {0.f, 0.f, 0.f, 0.f};
      #pragma unroll
      for (int ks = 0; ks < 2; ++ks){
        s8v a = *(const s8v*)&Hs[(rowbase + r) * 72 + ks*32 + q*8];
        s8v b = *(const s8v*)&W2h[(p*16 + r) * 72 + ks*32 + q*8];
        acc4 = __builtin_amdgcn_mfma_f32_16x16x32_bf16(a, b, acc4, 0, 0, 0);
      }
      #pragma unroll
      for (int rr = 0; rr < 4; ++rr)
        Cs[(rowbase + q*4 + rr) * 149 + p*16 + r] = acc4[rr];
    }

    __syncthreads();

    // ============== Phase 4: silu + tensor + segmented scatter ==============
    #pragma unroll 1
    for (int j = 0; j < 4; ++j){
      int uu = wq * 4 + j;
      int u  = h * 16 + uu;

      float wvj[9];
      #pragma unroll
      for (int p = 0; p < 9; ++p) wvj[p] = silu_f(Cs[el * 149 + p*16 + uu]);

      float x0 = xr[u];
      float xa = xr[32 + 3*u + 0], xb = xr[32 + 3*u + 1], xc = xr[32 + 3*u + 2];

      float a0 = wvj[0] * (B0 * x0)
               + wvj[4] * (B4[0]*xa + B4[1]*xb + B4[2]*xc);
      float a1[3];
      #pragma unroll
      for (int c = 0; c < 3; ++c)
        a1[c] = wvj[1] * (B1[c] * x0)
              + wvj[3] * (B3[c]*xa + B3[3+c]*xb + B3[6+c]*xc)
              + wvj[5] * (B5[c]*xa + B5[3+c]*xb + B5[6+c]*xc)
              + wvj[7] * (B7[c]*xa + B7[3+c]*xb + B7[6+c]*xc);
      float a2[5];
      #pragma unroll
      for (int c = 0; c < 5; ++c)
        a2[c] = wvj[2] * (B2[c] * x0)
              + wvj[6] * (B6[c]*xa + B6[5+c]*xb + B6[10+c]*xc)
              + wvj[8] * (B8[c]*xa + B8[5+c]*xb + B8[10+c]*xc);

      SEGSUM(a0);
      #pragma unroll
      for (int c = 0; c < 3; ++c) SEGSUM(a1[c]);
      #pragma unroll
      for (int c = 0; c < 5; ++c) SEGSUM(a2[c]);

      if (tail){
        if (USE_ROWS){
          dstrow[u] = a0;
          #pragma unroll
          for (int c = 0; c < 3; ++c) dstrow[32 + 3*u + c] = a1[c];
          #pragma unroll
          for (int c = 0; c < 5; ++c) dstrow[128 + 5*u + c] = a2[c];
        } else {
          unsafeAtomicAdd(&dstrow[u], a0);
          #pragma unroll
          for (int c = 0; c < 3; ++c) unsafeAtomicAdd(&dstrow[32 + 3*u + c], a1[c]);
          #pragma unroll
          for (int c = 0; c < 5; ++c) unsafeAtomicAdd(&dstrow[128 + 5*u + c], a2[c]);
        }
      }
    }

    // ---- stage W2^T half 1 ----
    if (h == 0){
      #pragma unroll 1
      for (int m = 0; m < 36; ++m){
        int flat = m * TPB + tid;
        int col  = flat % 144;
        int k    = flat / 144;
        int n    = (col >> 4) * 32 + 16 + (col & 15);
        W2h[col * 72 + k] = f2bf(W2[k * 288 + n]);
      }
    }
  }
}

// ---------------- combine: sum each dst's consecutive partial rows ----------
__global__ void combine_kernel(const float* __restrict__ rows,
                               const int* __restrict__ rows_dst,
                               float* __restrict__ out, int R)
{
  int r = blockIdx.x;
  if (r >= R) return;
  int d = rows_dst[r];
  if (d < 0) return;
  if (r + 1 < R && rows_dst[r + 1] == d) return;   // not last row of this dst
  int c = threadIdx.x;   // 64
  float acc[5] = {0.f, 0.f, 0.f, 0.f, 0.f};
  int rr = r;
  while (rr >= 0 && rows_dst[rr] == d){
    const float* row = rows + (size_t)rr * 288;
    #pragma unroll
    for (int i = 0; i < 5; ++i){ int ch = c + 64*i; if (ch < 288) acc[i] += row[ch]; }
    --rr;
  }
  float* o = out + (size_t)d * 288;
  #pragma unroll
  for (int i = 0; i < 5; ++i){ int ch = c + 64*i; if (ch < 288) o[ch] = acc[i]; }
}

// fallback (atomic per edge) if ws too small for CSR arrays
__global__ void __launch_bounds__(TPB, 2) tfn_atomic_kernel(
    const float* __restrict__ nf, const float* __restrict__ ef,
    const float* __restrict__ ev, const int* __restrict__ ei,
    const float* __restrict__ W0, const float* __restrict__ W1,
    const float* __restrict__ W2, const float* __restrict__ cg,
    float* __restrict__ out, int E)
{
  int e = blockIdx.x * TPB + threadIdx.x;
  if (e >= E) return;

  float f0[16];
  #pragma unroll
  for (int q = 0; q < 16; ++q) f0[q] = ef[(size_t)e*16 + q];
  float h1[64];
  #pragma unroll
  for (int j = 0; j < 64; ++j) h1[j] = 0.f;
  for (int k = 0; k < 64; ++k){
    float a = 0.f;
    #pragma unroll
    for (int q = 0; q < 16; ++q) a += f0[q] * W0[q*64 + k];
    float g = silu_f(a);
    #pragma unroll
    for (int j = 0; j < 64; ++j) h1[j] += g * W1[k*64 + j];
  }
  #pragma unroll
  for (int j = 0; j < 64; ++j) h1[j] = silu_f(h1[j]);

  float ex = ev[(size_t)e*3+0], eyv = ev[(size_t)e*3+1], ezv = ev[(size_t)e*3+2];
  float ri = __builtin_amdgcn_rcpf(sqrtf(ex*ex + eyv*eyv + ezv*ezv) + 1e-12f);
  float X = ex*ri, Y = eyv*ri, Z = ezv*ri;
  const float s3 = 1.7320508075688772f;
  float Y1v[3] = {Y, Z, X};
  float Y2v[5] = {s3*X*Y, s3*Y*Z, 0.5f*(3.f*Z*Z - 1.f), s3*X*Z, 0.5f*s3*(X*X - Y*Y)};

  float B0 = cg[0];
  float B1[3], B2[5], B3[9], B4[3], B5[9], B6[15], B7[9], B8[15];
  #pragma unroll
  for (int c = 0; c < 3; ++c){ float s = 0.f;
    #pragma unroll
    for (int b = 0; b < 3; ++b) s += cg[1 + b*3 + c] * Y1v[b];
    B1[c] = s; }
  #pragma unroll
  for (int c = 0; c < 5; ++c){ float s = 0.f;
    #pragma unroll
    for (int b = 0; b < 5; ++b) s += cg[10 + b*5 + c] * Y2v[b];
    B2[c] = s; }
  #pragma unroll
  for (int i = 0; i < 9; ++i) B3[i] = cg[35 + i];
  #pragma unroll
  for (int a = 0; a < 3; ++a){ float s = 0.f;
    #pragma unroll
    for (int b = 0; b < 3; ++b) s += cg[44 + a*3 + b] * Y1v[b];
    B4[a] = s; }
  #pragma unroll
  for (int a = 0; a < 3; ++a)
    #pragma unroll
    for (int c = 0; c < 3; ++c){ float s = 0.f;
      #pragma unroll
      for (int b = 0; b < 3; ++b) s += cg[53 + (a*3 + b)*3 + c] * Y1v[b];
      B5[a*3 + c] = s; }
  #pragma unroll
  for (int a = 0; a < 3; ++a)
    #pragma unroll
    for (int c = 0; c < 5; ++c){ float s = 0.f;
      #pragma unroll
      for (int b = 0; b < 3; ++b) s += cg[80 + (a*3 + b)*5 + c] * Y1v[b];
      B6[a*5 + c] = s; }
  #pragma unroll
  for (int a = 0; a < 3; ++a)
    #pragma unroll
    for (int c = 0; c < 3; ++c){ float s = 0.f;
      #pragma unroll
      for (int b = 0; b < 5; ++b) s += cg[125 + (a*5 + b)*3 + c] * Y2v[b];
      B7[a*3 + c] = s; }
  #pragma unroll
  for (int a = 0; a < 3; ++a)
    #pragma unroll
    for (int c = 0; c < 5; ++c){ float s = 0.f;
      #pragma unroll
      for (int b = 0; b < 5; ++b) s += cg[170 + (a*5 + b)*5 + c] * Y2v[b];
      B8[a*5 + c] = s; }

  int src = ei[2*e], dst = ei[2*e + 1];
  const float* xr = nf + (size_t)src * 128;
  float* orow = out + (size_t)dst * 288;

  for (int u = 0; u < 32; ++u){
    float wv[9];
    #pragma unroll
    for (int p = 0; p < 9; ++p) wv[p] = 0.f;
    #pragma unroll
    for (int k = 0; k < 64; ++k){
      float hk = h1[k];
      #pragma unroll
      for (int p = 0; p < 9; ++p) wv[p] += hk * W2[k*288 + p*32 + u];
    }
    #pragma unroll
    for (int p = 0; p < 9; ++p) wv[p] = silu_f(wv[p]);

    float x0 = xr[u];
    float xa = xr[32 + 3*u + 0], xb = xr[32 + 3*u + 1], xc = xr[32 + 3*u + 2];

    float a0 = wv[0] * (B0 * x0)
             + wv[4] * (B4[0]*xa + B4[1]*xb + B4[2]*xc);
    float a1[3];
    #pragma unroll
    for (int c = 0; c < 3; ++c)
      a1[c] = wv[1] * (B1[c] * x0)
            + wv[3] * (B3[c]*xa + B3[3+c]*xb + B3[6+c]*xc)
            + wv[5] * (B5[c]*xa + B5[3+c]*xb + B5[6+c]*xc)
            + wv[7] * (B7[c]*xa + B7[3+c]*xb + B7[6+c]*xc);
    float a2[5];
    #pragma unroll
    for (int c = 0; c < 5; ++c)
      a2[c] = wv[2] * (B2[c] * x0)
            + wv[6] * (B6[c]*xa + B6[5+c]*xb + B6[10+c]*xc)
            + wv[8] * (B8[c]*xa + B8[5+c]*xb + B8[10+c]*xc);

    unsafeAtomicAdd(&orow[u], a0);
    #pragma unroll
    for (int c = 0; c < 3; ++c) unsafeAtomicAdd(&orow[32 + 3*u + c], a1[c]);
    #pragma unroll
    for (int c = 0; c < 5; ++c) unsafeAtomicAdd(&orow[128 + 5*u + c], a2[c]);
  }
}

extern "C" void kernel_launch(void* const* d_in, const int* in_sizes, int n_in,
                              void* d_out, int out_size, void* d_ws, size_t ws_size,
                              hipStream_t stream)
{
  const float* nf = (const float*)d_in[0];
  const float* ef = (const float*)d_in[1];
  const float* ev = (const float*)d_in[2];
  const int*   ei = (const int*)  d_in[3];
  const float* W0 = (const float*)d_in[4];
  const float* W1 = (const float*)d_in[5];
  const float* W2 = (const float*)d_in[6];
  float* out = (float*)d_out;

  int E = in_sizes[3] / 2;
  int N = in_sizes[0] / 128;
  int R = E / 64 + N + 64;           // deterministic bound on partial rows

  // ws layout (4-byte units)
  float* cg     = (float*)d_ws;                        // 256
  int*   counts = (int*)d_ws + 256;                    // N
  int*   starts = counts + N;                          // N+1
  int*   cursor = starts + N + 1;                      // N
  int*   nzrank = cursor + N;                          // N
  int*   perm   = nzrank + N;                          // E
  size_t rd_off  = (size_t)256 + 4*(size_t)N + 1 + E;  // rows_dst
  int*   rows_dst = (int*)d_ws + rd_off;
  size_t rows_off = (rd_off + (size_t)R + 3) & ~(size_t)3;
  float* rows   = (float*)d_ws + rows_off;

  size_t need_csr  = (rd_off) * 4;
  size_t need_rows = (rows_off + (size_t)R * 288) * 4;

  int hb = (E + TPB - 1) / TPB;

  hipMemsetAsync(d_out, 0, (size_t)out_size * sizeof(float), stream);

  if (ws_size >= need_rows){
    hipMemsetAsync(counts, 0, (size_t)N * sizeof(int), stream);
    hipMemsetAsync(rows_dst, 0xFF, (size_t)R * sizeof(int), stream);   // -1
    hist_cg_kernel<<<hb + 1, TPB, 0, stream>>>(ei, counts, E, cg, hb);
    scan_kernel<<<1, 1024, 0, stream>>>(counts, starts, cursor, nzrank, N);
    perm_kernel<<<hb, TPB, 0, stream>>>(ei, cursor, perm, E);
    tfn_mfma_kernel<true><<<(E + TE - 1) / TE, TPB, 0, stream>>>(
        nf, ef, ev, ei, W0, W1, W2, cg, perm, nzrank, rows, rows_dst, out, E);
    combine_kernel<<<R, 64, 0, stream>>>(rows, rows_dst, out, R);
  } else if (ws_size >= need_csr){
    hipMemsetAsync(counts, 0, (size_t)N * sizeof(int), stream);
    hist_cg_kernel<<<hb + 1, TPB, 0, stream>>>(ei, counts, E, cg, hb);
    scan_kernel<<<1, 1024, 0, stream>>>(counts, starts, cursor, nzrank, N);
    perm_kernel<<<hb, TPB, 0, stream>>>(ei, cursor, perm, E);
    tfn_mfma_kernel<false><<<(E + TE - 1) / TE, TPB, 0, stream>>>(
        nf, ef, ev, ei, W0, W1, W2, cg, perm, nzrank, rows, rows_dst, out, E);
  } else {
    cg_init_kernel<<<1, 256, 0, stream>>>(cg);
    tfn_atomic_kernel<<<hb, TPB, 0, stream>>>(nf, ef, ev, ei, W0, W1, W2, cg, out, E);
  }
}

// Round 8
// 584.932 us; speedup vs baseline: 7.6729x; 1.0655x over previous
//
#include <hip/hip_runtime.h>
#include <hip/hip_bf16.h>
#include <math.h>

#define TPB 256
#define TE  64
#define HP  72     // Hs ushort pitch
#define WP  72     // W2h ushort pitch
#define CP  88     // Cs ushort pitch
#define QC  80     // staged cols per quarter (72 real + 8 zero)

typedef float  v4f __attribute__((ext_vector_type(4)));
typedef short  s8v __attribute__((ext_vector_type(8)));
typedef float  f4v __attribute__((ext_vector_type(4)));

// ---------------------------------------------------------------------------
// ws layout (4-byte units):
//   cg[256] | counts[N] | starts[N+1] | cursor[N] | nzrank[N] | perm[E]
//   | (align4) rows[R*288]
// R = E/64 + N + 64. Partial row index: ri = nzrank[dst] + sorted_pos/64.
// For dst d rows span nzrank[d]+(starts[d]>>6) .. nzrank[d]+((starts[d+1]-1)>>6)
// (every 64-window containing an edge of d gets exactly one tail write).
// ---------------------------------------------------------------------------

__device__ double dfact(int n){ double r = 1.0; for (int i = 2; i <= n; ++i) r *= (double)i; return r; }

__device__ void build_u(int l, double ur[5][5], double ui[5][5]){
  for (int i = 0; i < 5; ++i) for (int j = 0; j < 5; ++j){ ur[i][j] = 0.0; ui[i][j] = 0.0; }
  ur[l][l] = 1.0;
  double s = 1.0 / sqrt(2.0);
  for (int m = 1; m <= l; ++m){
    double sg = (m & 1) ? -1.0 : 1.0;
    ur[l + m][l + m] = sg * s;
    ur[l + m][l - m] = s;
    ui[l - m][l - m] = s;
    ui[l - m][l + m] = -sg * s;
  }
}

// One thread per CG output element (245). Re/im choice = parity rule.
__device__ void cg_compute(int tid, float* __restrict__ cg){
  if (tid >= 245) return;
  const int L1[9]  = {0,0,0,1,1,1,1,1,1};
  const int L2[9]  = {0,1,2,0,1,1,1,2,2};
  const int L3[9]  = {0,1,2,1,0,1,2,1,2};
  const int OFF[10] = {0,1,10,35,44,53,80,125,170,245};
  int p = 0;
  while (p < 8 && tid >= OFF[p+1]) ++p;
  int idx = tid - OFF[p];
  int l1 = L1[p], l2 = L2[p], l3 = L3[p];
  int n1 = 2*l1+1, n2 = 2*l2+1, n3 = 2*l3+1;
  int c = idx % n3; int ab = idx / n3; int b = ab % n2; int a = ab / n2;

  double Cc[5][5][5];
  for (int i = 0; i < 5; ++i) for (int j = 0; j < 5; ++j) for (int k = 0; k < 5; ++k) Cc[i][j][k] = 0.0;
  for (int m1 = -l1; m1 <= l1; ++m1) for (int m2 = -l2; m2 <= l2; ++m2){
    int m3 = m1 + m2;
    if (m3 < -l3 || m3 > l3) continue;
    double pref = sqrt((double)(2*l3+1) * dfact(l1+l2-l3) * dfact(l1-l2+l3) * dfact(-l1+l2+l3) / dfact(l1+l2+l3+1));
    pref *= sqrt(dfact(l3+m3)*dfact(l3-m3)*dfact(l1-m1)*dfact(l1+m1)*dfact(l2-m2)*dfact(l2+m2));
    double s = 0.0;
    for (int k = 0; k <= l1 + l2 - l3; ++k){
      int a0 = k, a1 = l1+l2-l3-k, a2 = l1-m1-k, a3 = l2+m2-k, a4 = l3-l2+m1+k, a5 = l3-l1-m2+k;
      if (a0 < 0 || a1 < 0 || a2 < 0 || a3 < 0 || a4 < 0 || a5 < 0) continue;
      double dd = dfact(a0)*dfact(a1)*dfact(a2)*dfact(a3)*dfact(a4)*dfact(a5);
      s += ((k & 1) ? -1.0 : 1.0) / dd;
    }
    Cc[m1+l1][m2+l2][m3+l3] = pref * s;
  }

  double U1r[5][5], U1i[5][5], U2r[5][5], U2i[5][5], U3r[5][5], U3i[5][5];
  build_u(l1, U1r, U1i); build_u(l2, U2r, U2i); build_u(l3, U3r, U3i);

  double sr = 0.0, si = 0.0;
  for (int m = 0; m < n1; ++m) for (int n = 0; n < n2; ++n) for (int o = 0; o < n3; ++o){
    double cc = Cc[m][n][o];
    if (cc == 0.0) continue;
    double xre = U1r[a][m], xim = U1i[a][m];
    double yre = U2r[b][n], yim = U2i[b][n];
    double zr = xre*yre - xim*yim, zi = xre*yim + xim*yre;
    double wr = U3r[c][o], wi = -U3i[c][o];
    double pr = zr*wr - zi*wi, pi = zr*wi + zi*wr;
    sr += pr * cc; si += pi * cc;
  }
  int use_re = (((l1 + l2 + l3) & 1) == 0);
  cg[tid] = (float)(use_re ? sr : si);
}

__global__ void cg_init_kernel(float* __restrict__ cg){
  cg_compute(threadIdx.x, cg);
}

// ---------------- CSR build (hist fused with cg) ----------------

__global__ void hist_cg_kernel(const int* __restrict__ ei, int* __restrict__ counts,
                               int E, float* __restrict__ cg, int nb){
  if ((int)blockIdx.x == nb){
    cg_compute(threadIdx.x, cg);
    return;
  }
  int e = blockIdx.x * TPB + threadIdx.x;
  if (e < E) atomicAdd(&counts[ei[2*e + 1]], 1);
}

__global__ void scan_kernel(const int* __restrict__ counts, int* __restrict__ starts,
                            int* __restrict__ cursor, int* __restrict__ nzrank, int N){
  __shared__ int part[1024];
  __shared__ int pnz[1024];
  int t = threadIdx.x;
  int T = (N + 1023) >> 10;
  int base = t * T;
  int s = 0, z = 0;
  for (int i = 0; i < T; ++i){
    int idx = base + i;
    if (idx < N){ int cc = counts[idx]; s += cc; z += (cc > 0); }
  }
  part[t] = s; pnz[t] = z; __syncthreads();
  for (int off = 1; off < 1024; off <<= 1){
    int v = (t >= off) ? part[t - off] : 0;
    int w = (t >= off) ? pnz[t - off] : 0;
    __syncthreads();
    part[t] += v; pnz[t] += w;
    __syncthreads();
  }
  int excl = (t == 0) ? 0 : part[t - 1];
  int enz  = (t == 0) ? 0 : pnz[t - 1];
  for (int i = 0; i < T; ++i){
    int idx = base + i;
    if (idx < N){
      starts[idx] = excl; cursor[idx] = excl; nzrank[idx] = enz;
      int cc = counts[idx];
      excl += cc; enz += (cc > 0);
    }
  }
  if (t == 1023) starts[N] = part[1023];
}

__global__ void perm_kernel(const int* __restrict__ ei, int* __restrict__ cursor,
                            int* __restrict__ perm, int E){
  int e = blockIdx.x * TPB + threadIdx.x;
  if (e < E){
    int pos = atomicAdd(&cursor[ei[2*e + 1]], 1);
    perm[pos] = e;
  }
}

// ---------------- helpers ----------------

__device__ __forceinline__ float silu_f(float x){
  float t = __expf(-x);
  return x * __builtin_amdgcn_rcpf(1.0f + t);
}

__device__ __forceinline__ ushort f2bf(float x){
  __hip_bfloat16 h = __float2bfloat16(x);   // RNE
  return *reinterpret_cast<ushort*>(&h);
}

__device__ __forceinline__ float bf2f(ushort u){
  uint v = (uint)u << 16;
  union { uint i; float f; } c; c.i = v;
  return c.f;
}

#define SEGSUM(v) { float _o; \
  _o = __shfl_up(v, 1);  v += samef[0]*_o; \
  _o = __shfl_up(v, 2);  v += samef[1]*_o; \
  _o = __shfl_up(v, 4);  v += samef[2]*_o; \
  _o = __shfl_up(v, 8);  v += samef[3]*_o; \
  _o = __shfl_up(v, 16); v += samef[4]*_o; \
  _o = __shfl_up(v, 32); v += samef[5]*_o; }

// ---------------------------------------------------------------------------
// Block-cooperative MFMA kernel, quarter-staged W2 (LDS 32000 B -> 5 blk/CU).
//  P1: per-thread MLP (edge=tid&63, j-quarter=tid>>6) -> Hs bf16
//  loop h=0..3: MFMA (5 tiles x 2 ksteps) -> Cs bf16; phase4 on 2 u per wave;
//               stage next W2 quarter during phase4 epoch.
// USE_ROWS: tails write partials to rows[] with plain stores; else atomics.
// ---------------------------------------------------------------------------
template<bool USE_ROWS>
__global__ void __launch_bounds__(TPB, 4) tfn_mfma_kernel(
    const float* __restrict__ nf, const float* __restrict__ ef,
    const float* __restrict__ ev, const int* __restrict__ ei,
    const float* __restrict__ W0, const float* __restrict__ W1,
    const float* __restrict__ W2, const float* __restrict__ cg,
    const int* __restrict__ perm, const int* __restrict__ nzrank,
    float* __restrict__ rows, float* __restrict__ out, int E)
{
  __shared__ ushort Hs[TE * HP];       // 9216 B
  __shared__ ushort W2h[QC * WP];      // 11520 B
  __shared__ ushort Cs[TE * CP];       // 11264 B  (bf16 C tile)

  const int tid  = threadIdx.x;
  const int el   = tid & 63;
  const int wq   = tid >> 6;
  const int lane = el;

  int t = blockIdx.x * TE + el;
  bool valid = (t < E);
  int e = perm[valid ? t : (E - 1)];
  int d = valid ? ei[2*e + 1] : -1;
  int src = ei[2*e];

  float samef[6];
  #pragma unroll
  for (int s = 0; s < 6; ++s){
    int off = 1 << s;
    int od = __shfl_up(d, off);
    samef[s] = (lane >= off && od == d) ? 1.0f : 0.0f;
  }
  int nd = __shfl_down(d, 1);
  bool tail = valid && ((lane == 63) || (nd != d));

  int ri = 0;
  if (USE_ROWS) ri = (d >= 0 ? nzrank[d] : 0) + (t >> 6);

  // ================= Phase 1: MLP layers 0+1 ========
  {
    float f0[16];
    const v4f* efv = (const v4f*)(ef + (size_t)e * 16);
    *(v4f*)&f0[0]  = efv[0];
    *(v4f*)&f0[4]  = efv[1];
    *(v4f*)&f0[8]  = efv[2];
    *(v4f*)&f0[12] = efv[3];

    float acc[64];
    #pragma unroll
    for (int j = 0; j < 64; ++j) acc[j] = 0.f;
    #pragma unroll
    for (int q = 0; q < 16; ++q){
      float fq = f0[q];
      const v4f* w0r = (const v4f*)(W0 + q * 64);
      #pragma unroll
      for (int k4 = 0; k4 < 16; ++k4){
        v4f w = w0r[k4];
        acc[4*k4+0] += fq * w.x; acc[4*k4+1] += fq * w.y;
        acc[4*k4+2] += fq * w.z; acc[4*k4+3] += fq * w.w;
      }
    }
    #pragma unroll
    for (int j = 0; j < 64; ++j) acc[j] = silu_f(acc[j]);

    float a1q[16];
    #pragma unroll
    for (int j = 0; j < 16; ++j) a1q[j] = 0.f;
    for (int k = 0; k < 64; ++k){
      float g = acc[k];
      const v4f* w1r = (const v4f*)(W1 + k * 64 + wq * 16);
      #pragma unroll
      for (int j4 = 0; j4 < 4; ++j4){
        v4f w = w1r[j4];
        a1q[4*j4+0] += g * w.x; a1q[4*j4+1] += g * w.y;
        a1q[4*j4+2] += g * w.z; a1q[4*j4+3] += g * w.w;
      }
    }
    #pragma unroll
    for (int j2 = 0; j2 < 8; ++j2){
      uint pk = (uint)f2bf(silu_f(a1q[2*j2])) | ((uint)f2bf(silu_f(a1q[2*j2+1])) << 16);
      *(uint*)&Hs[el * HP + wq * 16 + 2*j2] = pk;
    }
  }

  // ---- stage W2 quarter 0 ----
  #pragma unroll 1
  for (int m = 0; m < 20; ++m){
    int flat = m * TPB + tid;
    int col  = flat % QC;
    int k    = flat / QC;
    int p    = col >> 3, uu = col & 7;
    float v  = (p < 9) ? W2[k * 288 + p * 32 + uu] : 0.f;
    W2h[col * WP + k] = f2bf(v);
  }

  // ---- spherical harmonics + Y-contracted CG ----
  float ex = ev[(size_t)e*3+0], eyv = ev[(size_t)e*3+1], ezv = ev[(size_t)e*3+2];
  float ri2 = __builtin_amdgcn_rcpf(sqrtf(ex*ex + eyv*eyv + ezv*ezv) + 1e-12f);
  float X = ex*ri2, Y = eyv*ri2, Z = ezv*ri2;
  const float s3 = 1.7320508075688772f;
  float Y1v[3] = {Y, Z, X};
  float Y2v[5] = {s3*X*Y, s3*Y*Z, 0.5f*(3.f*Z*Z - 1.f), s3*X*Z, 0.5f*s3*(X*X - Y*Y)};

  float B0 = cg[0];
  float B1[3], B2[5], B3[9], B4[3], B5[9], B6[15], B7[9], B8[15];
  #pragma unroll
  for (int c = 0; c < 3; ++c){ float s = 0.f;
    #pragma unroll
    for (int b = 0; b < 3; ++b) s += cg[1 + b*3 + c] * Y1v[b];
    B1[c] = s; }
  #pragma unroll
  for (int c = 0; c < 5; ++c){ float s = 0.f;
    #pragma unroll
    for (int b = 0; b < 5; ++b) s += cg[10 + b*5 + c] * Y2v[b];
    B2[c] = s; }
  #pragma unroll
  for (int i = 0; i < 9; ++i) B3[i] = cg[35 + i];
  #pragma unroll
  for (int a = 0; a < 3; ++a){ float s = 0.f;
    #pragma unroll
    for (int b = 0; b < 3; ++b) s += cg[44 + a*3 + b] * Y1v[b];
    B4[a] = s; }
  #pragma unroll
  for (int a = 0; a < 3; ++a)
    #pragma unroll
    for (int c = 0; c < 3; ++c){ float s = 0.f;
      #pragma unroll
      for (int b = 0; b < 3; ++b) s += cg[53 + (a*3 + b)*3 + c] * Y1v[b];
      B5[a*3 + c] = s; }
  #pragma unroll
  for (int a = 0; a < 3; ++a)
    #pragma unroll
    for (int c = 0; c < 5; ++c){ float s = 0.f;
      #pragma unroll
      for (int b = 0; b < 3; ++b) s += cg[80 + (a*3 + b)*5 + c] * Y1v[b];
      B6[a*5 + c] = s; }
  #pragma unroll
  for (int a = 0; a < 3; ++a)
    #pragma unroll
    for (int c = 0; c < 3; ++c){ float s = 0.f;
      #pragma unroll
      for (int b = 0; b < 5; ++b) s += cg[125 + (a*5 + b)*3 + c] * Y2v[b];
      B7[a*3 + c] = s; }
  #pragma unroll
  for (int a = 0; a < 3; ++a)
    #pragma unroll
    for (int c = 0; c < 5; ++c){ float s = 0.f;
      #pragma unroll
      for (int b = 0; b < 5; ++b) s += cg[170 + (a*5 + b)*5 + c] * Y2v[b];
      B8[a*5 + c] = s; }

  const float* xr = nf + (size_t)src * 128;
  float* dstrow = USE_ROWS ? (rows + (size_t)ri * 288)
                           : (out + (size_t)(d < 0 ? 0 : d) * 288);

  const int r = lane & 15, q = lane >> 4;
  const int rowbase = wq * 16;

  #pragma unroll 1
  for (int h = 0; h < 4; ++h){
    __syncthreads();   // Hs+W2h(quarter h) ready; Cs consumed

    // ============== MFMA: 5 col-tiles x 2 k-steps ==============
    #pragma unroll 1
    for (int tt = 0; tt < 5; ++tt){
      f4v acc4 = {0.f, 0.f, 0.f, 0.f};
      #pragma unroll
      for (int ks = 0; ks < 2; ++ks){
        s8v a = *(const s8v*)&Hs[(rowbase + r) * HP + ks*32 + q*8];
        s8v b = *(const s8v*)&W2h[(tt*16 + r) * WP + ks*32 + q*8];
        acc4 = __builtin_amdgcn_mfma_f32_16x16x32_bf16(a, b, acc4, 0, 0, 0);
      }
      #pragma unroll
      for (int rr = 0; rr < 4; ++rr)
        Cs[(rowbase + q*4 + rr) * CP + tt*16 + r] = f2bf(acc4[rr]);
    }

    __syncthreads();   // Cs ready; W2h consumed

    // ============== Phase 4: silu + tensor + segmented scatter ==============
    #pragma unroll 1
    for (int j = 0; j < 2; ++j){
      int uuq = wq * 2 + j;        // 0..7 within quarter
      int u   = h * 8 + uuq;       // global channel

      float wvj[9];
      #pragma unroll
      for (int p = 0; p < 9; ++p) wvj[p] = silu_f(bf2f(Cs[el * CP + p*8 + uuq]));

      float x0 = xr[u];
      float xa = xr[32 + 3*u + 0], xb = xr[32 + 3*u + 1], xc = xr[32 + 3*u + 2];

      float a0 = wvj[0] * (B0 * x0)
               + wvj[4] * (B4[0]*xa + B4[1]*xb + B4[2]*xc);
      float a1[3];
      #pragma unroll
      for (int c = 0; c < 3; ++c)
        a1[c] = wvj[1] * (B1[c] * x0)
              + wvj[3] * (B3[c]*xa + B3[3+c]*xb + B3[6+c]*xc)
              + wvj[5] * (B5[c]*xa + B5[3+c]*xb + B5[6+c]*xc)
              + wvj[7] * (B7[c]*xa + B7[3+c]*xb + B7[6+c]*xc);
      float a2[5];
      #pragma unroll
      for (int c = 0; c < 5; ++c)
        a2[c] = wvj[2] * (B2[c] * x0)
              + wvj[6] * (B6[c]*xa + B6[5+c]*xb + B6[10+c]*xc)
              + wvj[8] * (B8[c]*xa + B8[5+c]*xb + B8[10+c]*xc);

      SEGSUM(a0);
      #pragma unroll
      for (int c = 0; c < 3; ++c) SEGSUM(a1[c]);
      #pragma unroll
      for (int c = 0; c < 5; ++c) SEGSUM(a2[c]);

      if (tail){
        if (USE_ROWS){
          dstrow[u] = a0;
          #pragma unroll
          for (int c = 0; c < 3; ++c) dstrow[32 + 3*u + c] = a1[c];
          #pragma unroll
          for (int c = 0; c < 5; ++c) dstrow[128 + 5*u + c] = a2[c];
        } else {
          unsafeAtomicAdd(&dstrow[u], a0);
          #pragma unroll
          for (int c = 0; c < 3; ++c) unsafeAtomicAdd(&dstrow[32 + 3*u + c], a1[c]);
          #pragma unroll
          for (int c = 0; c < 5; ++c) unsafeAtomicAdd(&dstrow[128 + 5*u + c], a2[c]);
        }
      }
    }

    // ---- stage next W2 quarter (W2h unread in this epoch) ----
    if (h < 3){
      int qn = h + 1;
      #pragma unroll 1
      for (int m = 0; m < 20; ++m){
        int flat = m * TPB + tid;
        int col  = flat % QC;
        int k    = flat / QC;
        int p    = col >> 3, uu = col & 7;
        float v  = (p < 9) ? W2[k * 288 + p * 32 + qn * 8 + uu] : 0.f;
        W2h[col * WP + k] = f2bf(v);
      }
    }
  }
}

// ---------------- combine: block per dst, closed-form row range -------------
__global__ void combine_kernel(const float* __restrict__ rows,
                               const int* __restrict__ starts,
                               const int* __restrict__ nzrank,
                               float* __restrict__ out, int N)
{
  int d = blockIdx.x;
  if (d >= N) return;
  int c = threadIdx.x;   // 64
  int s0 = starts[d], s1 = starts[d + 1];
  float a0 = 0.f, a1 = 0.f, a2 = 0.f, a3 = 0.f, a4 = 0.f;
  if (s1 > s0){
    int r0 = nzrank[d] + (s0 >> 6);
    int r1 = nzrank[d] + ((s1 - 1) >> 6);
    for (int r = r0; r <= r1; ++r){
      const float* row = rows + (size_t)r * 288;
      a0 += row[c];
      a1 += row[c + 64];
      a2 += row[c + 128];
      a3 += row[c + 192];
      if (c < 32) a4 += row[c + 256];
    }
  }
  float* o = out + (size_t)d * 288;
  o[c] = a0; o[c + 64] = a1; o[c + 128] = a2; o[c + 192] = a3;
  if (c < 32) o[c + 256] = a4;
}

// fallback (atomic per edge) if ws too small for CSR arrays
__global__ void __launch_bounds__(TPB, 2) tfn_atomic_kernel(
    const float* __restrict__ nf, const float* __restrict__ ef,
    const float* __restrict__ ev, const int* __restrict__ ei,
    const float* __restrict__ W0, const float* __restrict__ W1,
    const float* __restrict__ W2, const float* __restrict__ cg,
    float* __restrict__ out, int E)
{
  int e = blockIdx.x * TPB + threadIdx.x;
  if (e >= E) return;

  float f0[16];
  #pragma unroll
  for (int q = 0; q < 16; ++q) f0[q] = ef[(size_t)e*16 + q];
  float h1[64];
  #pragma unroll
  for (int j = 0; j < 64; ++j) h1[j] = 0.f;
  for (int k = 0; k < 64; ++k){
    float a = 0.f;
    #pragma unroll
    for (int q = 0; q < 16; ++q) a += f0[q] * W0[q*64 + k];
    float g = silu_f(a);
    #pragma unroll
    for (int j = 0; j < 64; ++j) h1[j] += g * W1[k*64 + j];
  }
  #pragma unroll
  for (int j = 0; j < 64; ++j) h1[j] = silu_f(h1[j]);

  float ex = ev[(size_t)e*3+0], eyv = ev[(size_t)e*3+1], ezv = ev[(size_t)e*3+2];
  float ri = __builtin_amdgcn_rcpf(sqrtf(ex*ex + eyv*eyv + ezv*ezv) + 1e-12f);
  float X = ex*ri, Y = eyv*ri, Z = ezv*ri;
  const float s3 = 1.7320508075688772f;
  float Y1v[3] = {Y, Z, X};
  float Y2v[5] = {s3*X*Y, s3*Y*Z, 0.5f*(3.f*Z*Z - 1.f), s3*X*Z, 0.5f*s3*(X*X - Y*Y)};

  float B0 = cg[0];
  float B1[3], B2[5], B3[9], B4[3], B5[9], B6[15], B7[9], B8[15];
  #pragma unroll
  for (int c = 0; c < 3; ++c){ float s = 0.f;
    #pragma unroll
    for (int b = 0; b < 3; ++b) s += cg[1 + b*3 + c] * Y1v[b];
    B1[c] = s; }
  #pragma unroll
  for (int c = 0; c < 5; ++c){ float s = 0.f;
    #pragma unroll
    for (int b = 0; b < 5; ++b) s += cg[10 + b*5 + c] * Y2v[b];
    B2[c] = s; }
  #pragma unroll
  for (int i = 0; i < 9; ++i) B3[i] = cg[35 + i];
  #pragma unroll
  for (int a = 0; a < 3; ++a){ float s = 0.f;
    #pragma unroll
    for (int b = 0; b < 3; ++b) s += cg[44 + a*3 + b] * Y1v[b];
    B4[a] = s; }
  #pragma unroll
  for (int a = 0; a < 3; ++a)
    #pragma unroll
    for (int c = 0; c < 3; ++c){ float s = 0.f;
      #pragma unroll
      for (int b = 0; b < 3; ++b) s += cg[53 + (a*3 + b)*3 + c] * Y1v[b];
      B5[a*3 + c] = s; }
  #pragma unroll
  for (int a = 0; a < 3; ++a)
    #pragma unroll
    for (int c = 0; c < 5; ++c){ float s = 0.f;
      #pragma unroll
      for (int b = 0; b < 3; ++b) s += cg[80 + (a*3 + b)*5 + c] * Y1v[b];
      B6[a*5 + c] = s; }
  #pragma unroll
  for (int a = 0; a < 3; ++a)
    #pragma unroll
    for (int c = 0; c < 3; ++c){ float s = 0.f;
      #pragma unroll
      for (int b = 0; b < 5; ++b) s += cg[125 + (a*5 + b)*3 + c] * Y2v[b];
      B7[a*3 + c] = s; }
  #pragma unroll
  for (int a = 0; a < 3; ++a)
    #pragma unroll
    for (int c = 0; c < 5; ++c){ float s = 0.f;
      #pragma unroll
      for (int b = 0; b < 5; ++b) s += cg[170 + (a*5 + b)*5 + c] * Y2v[b];
      B8[a*5 + c] = s; }

  int src = ei[2*e], dst = ei[2*e + 1];
  const float* xr = nf + (size_t)src * 128;
  float* orow = out + (size_t)dst * 288;

  for (int u = 0; u < 32; ++u){
    float wv[9];
    #pragma unroll
    for (int p = 0; p < 9; ++p) wv[p] = 0.f;
    #pragma unroll
    for (int k = 0; k < 64; ++k){
      float hk = h1[k];
      #pragma unroll
      for (int p = 0; p < 9; ++p) wv[p] += hk * W2[k*288 + p*32 + u];
    }
    #pragma unroll
    for (int p = 0; p < 9; ++p) wv[p] = silu_f(wv[p]);

    float x0 = xr[u];
    float xa = xr[32 + 3*u + 0], xb = xr[32 + 3*u + 1], xc = xr[32 + 3*u + 2];

    float a0 = wv[0] * (B0 * x0)
             + wv[4] * (B4[0]*xa + B4[1]*xb + B4[2]*xc);
    float a1[3];
    #pragma unroll
    for (int c = 0; c < 3; ++c)
      a1[c] = wv[1] * (B1[c] * x0)
            + wv[3] * (B3[c]*xa + B3[3+c]*xb + B3[6+c]*xc)
            + wv[5] * (B5[c]*xa + B5[3+c]*xb + B5[6+c]*xc)
            + wv[7] * (B7[c]*xa + B7[3+c]*xb + B7[6+c]*xc);
    float a2[5];
    #pragma unroll
    for (int c = 0; c < 5; ++c)
      a2[c] = wv[2] * (B2[c] * x0)
            + wv[6] * (B6[c]*xa + B6[5+c]*xb + B6[10+c]*xc)
            + wv[8] * (B8[c]*xa + B8[5+c]*xb + B8[10+c]*xc);

    unsafeAtomicAdd(&orow[u], a0);
    #pragma unroll
    for (int c = 0; c < 3; ++c) unsafeAtomicAdd(&orow[32 + 3*u + c], a1[c]);
    #pragma unroll
    for (int c = 0; c < 5; ++c) unsafeAtomicAdd(&orow[128 + 5*u + c], a2[c]);
  }
}

extern "C" void kernel_launch(void* const* d_in, const int* in_sizes, int n_in,
                              void* d_out, int out_size, void* d_ws, size_t ws_size,
                              hipStream_t stream)
{
  const float* nf = (const float*)d_in[0];
  const float* ef = (const float*)d_in[1];
  const float* ev = (const float*)d_in[2];
  const int*   ei = (const int*)  d_in[3];
  const float* W0 = (const float*)d_in[4];
  const float* W1 = (const float*)d_in[5];
  const float* W2 = (const float*)d_in[6];
  float* out = (float*)d_out;

  int E = in_sizes[3] / 2;
  int N = in_sizes[0] / 128;
  int R = E / 64 + N + 64;           // bound on partial rows

  // ws layout (4-byte units)
  float* cg     = (float*)d_ws;                        // 256
  int*   counts = (int*)d_ws + 256;                    // N
  int*   starts = counts + N;                          // N+1
  int*   cursor = starts + N + 1;                      // N
  int*   nzrank = cursor + N;                          // N
  int*   perm   = nzrank + N;                          // E
  size_t base_off = (size_t)256 + 4*(size_t)N + 1 + E;
  size_t rows_off = (base_off + 3) & ~(size_t)3;
  float* rows   = (float*)d_ws + rows_off;

  size_t need_csr  = base_off * 4;
  size_t need_rows = (rows_off + (size_t)R * 288) * 4;

  int hb = (E + TPB - 1) / TPB;

  if (ws_size >= need_rows){
    hipMemsetAsync(counts, 0, (size_t)N * sizeof(int), stream);
    hist_cg_kernel<<<hb + 1, TPB, 0, stream>>>(ei, counts, E, cg, hb);
    scan_kernel<<<1, 1024, 0, stream>>>(counts, starts, cursor, nzrank, N);
    perm_kernel<<<hb, TPB, 0, stream>>>(ei, cursor, perm, E);
    tfn_mfma_kernel<true><<<(E + TE - 1) / TE, TPB, 0, stream>>>(
        nf, ef, ev, ei, W0, W1, W2, cg, perm, nzrank, rows, out, E);
    combine_kernel<<<N, 64, 0, stream>>>(rows, starts, nzrank, out, N);
  } else if (ws_size >= need_csr){
    hipMemsetAsync(d_out, 0, (size_t)out_size * sizeof(float), stream);
    hipMemsetAsync(counts, 0, (size_t)N * sizeof(int), stream);
    hist_cg_kernel<<<hb + 1, TPB, 0, stream>>>(ei, counts, E, cg, hb);
    scan_kernel<<<1, 1024, 0, stream>>>(counts, starts, cursor, nzrank, N);
    perm_kernel<<<hb, TPB, 0, stream>>>(ei, cursor, perm, E);
    tfn_mfma_kernel<false><<<(E + TE - 1) / TE, TPB, 0, stream>>>(
        nf, ef, ev, ei, W0, W1, W2, cg, perm, nzrank, rows, out, E);
  } else {
    hipMemsetAsync(d_out, 0, (size_t)out_size * sizeof(float), stream);
    cg_init_kernel<<<1, 256, 0, stream>>>(cg);
    tfn_atomic_kernel<<<hb, TPB, 0, stream>>>(nf, ef, ev, ei, W0, W1, W2, cg, out, E);
  }
}